// Round 2
// 553.358 us; speedup vs baseline: 1.2030x; 1.2030x over previous
//
#include <hip/hip_runtime.h>
#include <hip/hip_bf16.h>

// All float inputs/outputs are FP32 (verified round 3: dtype-detect ran the
// fp32 path and passed; every bf16-hardcoded round NaN'd on reinterpreted
// fp32 bits). bf16 is used only internally for MFMA operands/intermediates.

#define NN 8192
#define KNBR 32
#define DD 768
#define CPC 128
#define HH 8
#define FEATD 1792
#define QKVD 1536
#define PTSD 576      // H * 24 * 3
#define PAIR_ROW 4096 // K*CP fp32 elements per residue row of `pair`

typedef __hip_bfloat16 bf16;
typedef __attribute__((ext_vector_type(8))) short s8;   // 8 bf16 (4 VGPRs)
typedef __attribute__((ext_vector_type(4))) float f4;   // MFMA accumulator
typedef __attribute__((ext_vector_type(4))) float fv4;  // ext-vector float4 (builtin-safe)

__device__ __forceinline__ float b2f(bf16 v) { return __bfloat162float(v); }
__device__ __forceinline__ bf16 f2b(float v) { return __float2bfloat16(v); }
__device__ __forceinline__ unsigned short f2u(float v) {
    bf16 h = __float2bfloat16(v);
    return *(unsigned short*)&h;
}

// ---------------------------------------------------------------- frames ----
__global__ __launch_bounds__(256) void frames_kernel(const float* __restrict__ pos,
                                                     float* __restrict__ Rm,
                                                     float* __restrict__ tv) {
    int n = blockIdx.x * blockDim.x + threadIdx.x;
    if (n >= NN) return;
    const float* p = pos + (size_t)n * 42;  // (14,3): N, CA, C first three
    float nx[3], ca[3], cc[3];
#pragma unroll
    for (int j = 0; j < 3; ++j) { nx[j] = p[j]; ca[j] = p[3+j]; cc[j] = p[6+j]; }
    float v1[3], v2[3], e1[3], e2[3], e3[3];
#pragma unroll
    for (int j = 0; j < 3; ++j) { v1[j] = cc[j] - ca[j]; v2[j] = nx[j] - ca[j]; }
    float s1 = v1[0]*v1[0] + v1[1]*v1[1] + v1[2]*v1[2];
    float r1 = 1.0f / sqrtf(s1 + 1e-8f);
#pragma unroll
    for (int j = 0; j < 3; ++j) e1[j] = v1[j] * r1;
    float d = v2[0]*e1[0] + v2[1]*e1[1] + v2[2]*e1[2];
    float u2[3];
#pragma unroll
    for (int j = 0; j < 3; ++j) u2[j] = v2[j] - d * e1[j];
    float s2 = u2[0]*u2[0] + u2[1]*u2[1] + u2[2]*u2[2];
    float r2 = 1.0f / sqrtf(s2 + 1e-8f);
#pragma unroll
    for (int j = 0; j < 3; ++j) e2[j] = u2[j] * r2;
    e3[0] = e1[1]*e2[2] - e1[2]*e2[1];
    e3[1] = e1[2]*e2[0] - e1[0]*e2[2];
    e3[2] = e1[0]*e2[1] - e1[1]*e2[0];
    // R = stack([e1,e2,e3], axis=-1): e_j is column j
#pragma unroll
    for (int i = 0; i < 3; ++i) {
        Rm[(size_t)n*9 + i*3 + 0] = e1[i];
        Rm[(size_t)n*9 + i*3 + 1] = e2[i];
        Rm[(size_t)n*9 + i*3 + 2] = e3[i];
        tv[(size_t)n*3 + i] = ca[i];
    }
}

// ------------------------------------------------- per-row LN statistics ----
__global__ __launch_bounds__(256) void rowstat_kernel(const float* __restrict__ local,
                                                      float* __restrict__ stat) {
    int n = blockIdx.x, tid = threadIdx.x;
    const float* row = local + (size_t)n * DD;
    float v[3];
#pragma unroll
    for (int e = 0; e < 3; ++e) v[e] = row[tid + 256*e];
    __shared__ float red[256];
    red[tid] = v[0] + v[1] + v[2];
    __syncthreads();
    for (int st = 128; st > 0; st >>= 1) {
        if (tid < st) red[tid] += red[tid + st];
        __syncthreads();
    }
    float mean = red[0] * (1.0f / DD);
    __syncthreads();
    float d0 = v[0]-mean, d1 = v[1]-mean, d2 = v[2]-mean;
    red[tid] = d0*d0 + d1*d1 + d2*d2;
    __syncthreads();
    for (int st = 128; st > 0; st >>= 1) {
        if (tid < st) red[tid] += red[tid + st];
        __syncthreads();
    }
    if (tid == 0) {
        stat[n*2]     = mean;
        stat[n*2 + 1] = rsqrtf(red[0] * (1.0f / DD) + 1e-5f);
    }
}

// ----------------------------------------------------- weight transpose -----
// W: K x N (row-major FP32) -> Wt: Npad x K (row-major bf16), zero rows >= N.
// Optional output-column permutation (cn != 0): segregates interleaved
// per-head segments, old col = h*group + seg*cn + c  ->  seg*segsz + h*cn + c.
// Used so attn gathers read contiguous q|k|v (and qg|kg|vg) blocks.
__global__ __launch_bounds__(256) void transpose_kernel(const float* __restrict__ W,
                                                        bf16* __restrict__ Wt,
                                                        int K, int N,
                                                        int group, int cn, int segsz) {
    __shared__ bf16 tile[32][33];
    int n0 = blockIdx.x * 32, k0 = blockIdx.y * 32;
    int tid = threadIdx.x;
    int r = tid >> 5, c = tid & 31;
    for (int rr = r; rr < 32; rr += 8) {
        int n = n0 + c;
        tile[rr][c] = (n < N) ? f2b(W[(size_t)(k0 + rr) * N + n]) : f2b(0.0f);
    }
    __syncthreads();
    for (int rr = r; rr < 32; rr += 8) {
        int n = n0 + rr;
        int pn = n;
        if (cn != 0 && n < N) {
            int hh = n / group, rm = n % group;
            pn = (rm / cn) * segsz + hh * cn + (rm % cn);
        }
        Wt[(size_t)pn * K + k0 + c] = tile[c][rr];
    }
}

// ------------------------------------------------------------ MFMA GEMM -----
// C[M x ncols] = A'[M x K] @ Bt^T   (Bt stored N x K bf16, pre-transposed)
// 128x128 tile, BK=32, 4 waves x (4x4) mfma_f32_16x16x32_bf16, manual staging.
// LNA=1: A is FP32; A' = LayerNorm(A) -> bf16 fused into staging.
// LNA=0: A is bf16 rows (feats in pair buffer), lda in bf16 elements.
// OUTF32=1: fp32 C (+fp32 bias if BIAS); else bf16 C.
template<int LNA, int OUTF32, int BIAS>
__global__ __launch_bounds__(256) void mfma_gemm(const void* __restrict__ A, int lda,
                                                 const float* __restrict__ stat,
                                                 const float* __restrict__ lns,
                                                 const float* __restrict__ lnb,
                                                 const bf16* __restrict__ Bt,
                                                 void* __restrict__ C, int ldc,
                                                 int ncols,
                                                 const float* __restrict__ bias,
                                                 int K) {
    __shared__ short As[128 * 32];   // [row][k] bf16 bits, 8 KB
    __shared__ short Bs[128 * 32];   // [n][k]  bf16 bits, 8 KB
    int tid = threadIdx.x;
    int w = tid >> 6, lane = tid & 63;
    int q = lane >> 4, lr = lane & 15;
    int m0 = blockIdx.y * 128, n0 = blockIdx.x * 128;

    f4 acc[4][4] = {};

    for (int k0 = 0; k0 < K; k0 += 32) {
        // ---- stage B tile: 512 x 16B chunks, 2 per thread ----
#pragma unroll
        for (int i = 0; i < 2; ++i) {
            int ch = i * 256 + tid;                 // chunk id 0..511
            const uint4* g =
                (const uint4*)(Bt + (size_t)(n0 + (ch >> 2)) * K + k0) + (ch & 3);
            *(uint4*)(Bs + (size_t)ch * 8) = *g;
        }
        // ---- stage A tile ----
#pragma unroll
        for (int i = 0; i < 2; ++i) {
            int ch = i * 256 + tid;
            int r = ch >> 2, c8 = (ch & 3) * 8;
            if (LNA) {
                const float* ap = (const float*)A + (size_t)(m0 + r) * lda + k0 + c8;
                float4 a0 = *(const float4*)ap;
                float4 a1 = *(const float4*)(ap + 4);
                float4 s0 = *(const float4*)(lns + k0 + c8);
                float4 s1 = *(const float4*)(lns + k0 + c8 + 4);
                float4 o0 = *(const float4*)(lnb + k0 + c8);
                float4 o1 = *(const float4*)(lnb + k0 + c8 + 4);
                float mean = stat[(m0 + r) * 2];
                float rstd = stat[(m0 + r) * 2 + 1];
                float av[8] = {a0.x,a0.y,a0.z,a0.w,a1.x,a1.y,a1.z,a1.w};
                float sv[8] = {s0.x,s0.y,s0.z,s0.w,s1.x,s1.y,s1.z,s1.w};
                float ov[8] = {o0.x,o0.y,o0.z,o0.w,o1.x,o1.y,o1.z,o1.w};
                unsigned short outp[8];
#pragma unroll
                for (int j = 0; j < 8; ++j)
                    outp[j] = f2u((av[j] - mean) * rstd * sv[j] + ov[j]);
                *(uint4*)(As + (size_t)ch * 8) = *(const uint4*)outp;
            } else {
                const uint4* g =
                    (const uint4*)((const bf16*)A + (size_t)(m0 + r) * lda + k0 + c8);
                *(uint4*)(As + (size_t)ch * 8) = *g;
            }
        }
        __syncthreads();

        // ---- fragments + 16 MFMAs ----
        const short* Ab = As + ((w & 1) * 64 + lr) * 32 + q * 8;
        const short* Bb = Bs + ((w >> 1) * 64 + lr) * 32 + q * 8;
        s8 af[4], bfr[4];
#pragma unroll
        for (int i = 0; i < 4; ++i) af[i] = *(const s8*)(Ab + i * 16 * 32);
#pragma unroll
        for (int j = 0; j < 4; ++j) bfr[j] = *(const s8*)(Bb + j * 16 * 32);
#pragma unroll
        for (int i = 0; i < 4; ++i)
#pragma unroll
            for (int j = 0; j < 4; ++j)
                acc[i][j] = __builtin_amdgcn_mfma_f32_16x16x32_bf16(
                    af[i], bfr[j], acc[i][j], 0, 0, 0);
        __syncthreads();
    }

    // ---- epilogue: C/D layout col=lane&15, row=(lane>>4)*4+reg ----
    int mb = m0 + (w & 1) * 64, nb = n0 + (w >> 1) * 64;
#pragma unroll
    for (int i = 0; i < 4; ++i) {
#pragma unroll
        for (int j = 0; j < 4; ++j) {
            int col = nb + j * 16 + lr;
            int row0 = mb + i * 16 + q * 4;
            if (col < ncols) {
#pragma unroll
                for (int r = 0; r < 4; ++r) {
                    float v = acc[i][j][r];
                    if (BIAS) v += bias[col];
                    if (OUTF32) ((float*)C)[(size_t)(row0 + r) * ldc + col] = v;
                    else ((unsigned short*)C)[(size_t)(row0 + r) * ldc + col] = f2u(v);
                }
            }
        }
    }
}

// --------------------------------------------------------- per-head LN q,k --
// qkv layout is now segregated: q at [0,512), k at [512,1024), v at [1024,1536)
// with per-head 64-wide slices (h*64+c) in each segment.
__global__ __launch_bounds__(256) void ln_qk_kernel(bf16* __restrict__ qkv,
                                                    const float* __restrict__ qs,
                                                    const float* __restrict__ qb,
                                                    const float* __restrict__ ks,
                                                    const float* __restrict__ kb) {
    int tid = threadIdx.x;
    int pi = blockIdx.x * 4 + (tid >> 6);  // (n,h) pair index
    int lane = tid & 63;
    bf16* base = qkv + (size_t)(pi >> 3) * QKVD + (pi & 7) * 64;
#pragma unroll
    for (int part = 0; part < 2; ++part) {
        int off = part * 512;
        const float* sc = part ? ks : qs;
        const float* of = part ? kb : qb;
        float v = b2f(base[off + lane]);
        float s = v;
#pragma unroll
        for (int m = 32; m > 0; m >>= 1) s += __shfl_xor(s, m, 64);
        float mean = s * (1.0f / 64.0f);
        float d = v - mean;
        float sq = d * d;
#pragma unroll
        for (int m = 32; m > 0; m >>= 1) sq += __shfl_xor(sq, m, 64);
        float inv = rsqrtf(sq * (1.0f / 64.0f) + 1e-5f);
        base[off + lane] = f2b(d * inv * sc[lane] + of[lane]);
    }
}

// -------------------------------------------------------- rotate points -----
// Layout-agnostic: operates on all 192 triplets of a row regardless of the
// qg|kg|vg segment ordering (rotation is per-triplet).
__global__ __launch_bounds__(256) void rotate_pts_kernel(float* __restrict__ pts,
                                                         const float* __restrict__ Rm,
                                                         const float* __restrict__ tv) {
    int idx = blockIdx.x * blockDim.x + threadIdx.x;  // over N*192
    if (idx >= NN * 192) return;
    int n = idx / 192;
    int rem = idx % 192;
    float* base = pts + (size_t)n * PTSD + rem * 3;
    float r0 = base[0], r1 = base[1], r2 = base[2];
    const float* R = Rm + (size_t)n * 9;
    const float* t = tv + (size_t)n * 3;
    base[0] = R[0]*r0 + R[1]*r1 + R[2]*r2 + t[0];
    base[1] = R[3]*r0 + R[4]*r1 + R[5]*r2 + t[1];
    base[2] = R[6]*r0 + R[7]*r1 + R[8]*r2 + t[2];
}

// ------------------------------------------------------------- attention ----
// Segregated layouts:
//   qkv row: [q: h*64+c | 512 + k: h*64+c | 1024 + v: h*64+c]
//   pts row: [qg: h*24+e | 192 + kg: h*24+e | 384 + vg: h*24+e]  (e = p*3+d)
// Logits phase is wave-parallel: each wave owns 8 k's; 8 lanes per head do
// 16B vector gathers + shfl reduction. q/qg/Wb-column hoisted to registers.
// pair row staged with NONTEMPORAL loads (streaming 134MB must not evict the
// 44MB of qkv+pts that the random gathers re-read from L2/L3).
// Writes feats (bf16) into the pair buffer's own row region (safe: row fully
// staged into LDS before the first feats write).
__global__ __launch_bounds__(256) void attn_kernel(const bf16* __restrict__ qkv,
                                                   const float* __restrict__ pts,
                                                   const float* __restrict__ Rm,
                                                   const float* __restrict__ tv,
                                                   float* __restrict__ pair,
                                                   const int* __restrict__ nbr,
                                                   const float* __restrict__ Wb,
                                                   const float* __restrict__ gamma) {
    int n = blockIdx.x;
    int tid = threadIdx.x;
    int w = tid >> 6, lane = tid & 63;
    int h = lane >> 3, cg = lane & 7;

    __shared__ float pairS[32][132];  // pad 132: float4-aligned, conflict-free
    __shared__ float logitS[32][8];
    __shared__ float attnS[32][8];
    __shared__ float gS[192];
    __shared__ int nbS[32];
    __shared__ float dfS[8];

    // ---- stage pair row (nontemporal: evict-first, keep L3 for gathers) ----
    const fv4* pr4 = (const fv4*)(pair + (size_t)n * PAIR_ROW);
    for (int e = tid; e < 1024; e += 256) {
        fv4 u = __builtin_nontemporal_load(pr4 + e);
        int k = e >> 5, c0 = (e & 31) * 4;
        *(fv4*)&pairS[k][c0] = u;
    }
    if (tid < 32) nbS[tid] = nbr[(size_t)n * KNBR + tid];
    if (tid < 8) dfS[tid] = log1pf(expf(gamma[tid])) * (1.0f / 12.0f);

    // ---- hoist loop-invariants into registers ----
    float qreg[8];
    {
        uint4 qv = *(const uint4*)(qkv + (size_t)n * QKVD + h * 64 + cg * 8);
        const unsigned short* qs = (const unsigned short*)&qv;
#pragma unroll
        for (int j = 0; j < 8; ++j) qreg[j] = b2f(*(const bf16*)&qs[j]);
    }
    fv4 qg = (fv4)(0.0f);
    if (cg < 6) qg = *(const fv4*)(pts + (size_t)n * PTSD + h * 24 + cg * 4);
    float wb[16];
#pragma unroll
    for (int j = 0; j < 16; ++j) wb[j] = Wb[(cg + 8 * j) * 8 + h];  // Wb 4KB, L2-hot

    __syncthreads();

    // ---- logits: wave w owns k = w*8 .. w*8+7 ----
#pragma unroll
    for (int kk = 0; kk < 8; ++kk) {
        int k = w * 8 + kk;
        int nb = nbS[k];
        // dot(q_h, k_h): 8 lanes x uint4 (8 bf16 each)
        uint4 kv = *(const uint4*)(qkv + (size_t)nb * QKVD + 512 + h * 64 + cg * 8);
        const unsigned short* ks = (const unsigned short*)&kv;
        float dot = 0.0f;
#pragma unroll
        for (int j = 0; j < 8; ++j) dot += qreg[j] * b2f(*(const bf16*)&ks[j]);
        // dist: 6 lanes x float4 (24 floats of k_g)
        float d2 = 0.0f;
        if (cg < 6) {
            fv4 kg = *(const fv4*)(pts + (size_t)nb * PTSD + 192 + h * 24 + cg * 4);
            float dx = qg.x - kg.x, dy = qg.y - kg.y, dz = qg.z - kg.z, dw = qg.w - kg.w;
            d2 = dx*dx + dy*dy + dz*dz + dw*dw;
        }
        // bias: 8 lanes x 16 strided cols (conflict-free LDS)
        float bias = 0.0f;
#pragma unroll
        for (int j = 0; j < 16; ++j) bias += pairS[k][cg + 8 * j] * wb[j];

        float val = 0.125f * dot + bias - dfS[h] * d2;
        val += __shfl_xor(val, 1, 64);
        val += __shfl_xor(val, 2, 64);
        val += __shfl_xor(val, 4, 64);
        if (cg == 0) logitS[k][h] = 0.5773502691896258f * val;
    }
    __syncthreads();

    // ---- softmax over k, one wave: lane = h*8 + j, j owns k = j + 8i ----
    if (tid < 64) {
        int hh = tid >> 3, j = tid & 7;
        float l[4];
        float m = -1e30f;
#pragma unroll
        for (int i = 0; i < 4; ++i) { l[i] = logitS[j + 8 * i][hh]; m = fmaxf(m, l[i]); }
        m = fmaxf(m, __shfl_xor(m, 1, 64));
        m = fmaxf(m, __shfl_xor(m, 2, 64));
        m = fmaxf(m, __shfl_xor(m, 4, 64));
        float s = 0.0f;
#pragma unroll
        for (int i = 0; i < 4; ++i) { l[i] = expf(l[i] - m); s += l[i]; }
        s += __shfl_xor(s, 1, 64);
        s += __shfl_xor(s, 2, 64);
        s += __shfl_xor(s, 4, 64);
        float inv = 1.0f / s;
#pragma unroll
        for (int i = 0; i < 4; ++i) attnS[j + 8 * i][hh] = l[i] * inv;
    }
    __syncthreads();

    bf16* fr = (bf16*)(pair + (size_t)n * PAIR_ROW);  // feats row, 3584B of 16KB
    // ---- out_pair: 1024 = H*CP ----
    for (int e = tid; e < 1024; e += 256) {
        int hh = e >> 7, c = e & 127;
        float acc = 0.0f;
#pragma unroll
        for (int k = 0; k < KNBR; ++k) acc += attnS[k][hh] * pairS[k][c];
        fr[e] = f2b(acc);
    }
    // ---- out_scalar: 512 = H*S (coalesced v gathers) ----
    for (int e = tid; e < 512; e += 256) {
        int hh = e >> 6, c = e & 63;
        float acc = 0.0f;
#pragma unroll
        for (int k = 0; k < KNBR; ++k)
            acc += attnS[k][hh] * b2f(qkv[(size_t)nbS[k] * QKVD + 1024 + hh * 64 + c]);
        fr[1024 + e] = f2b(acc);
    }
    // ---- op: 192 threads, coalesced per-k v_g rows ----
    if (tid < 192) {
        int hh = tid / 24;
        float acc = 0.0f;
#pragma unroll
        for (int k = 0; k < KNBR; ++k)
            acc += attnS[k][hh] * pts[(size_t)nbS[k] * PTSD + 384 + tid];
        gS[tid] = acc;
    }
    __syncthreads();
    if (tid < 64) {
        int hh = tid >> 3, p = tid & 7;
        const float* t = tv + (size_t)n * 3;
        const float* R = Rm + (size_t)n * 9;
        float gx = gS[hh * 24 + p * 3 + 0] - t[0];
        float gy = gS[hh * 24 + p * 3 + 1] - t[1];
        float gz = gS[hh * 24 + p * 3 + 2] - t[2];
        // einsum('nji,...j->...i') = R^T g
        float o0 = R[0]*gx + R[3]*gy + R[6]*gz;
        float o1 = R[1]*gx + R[4]*gy + R[7]*gz;
        float o2 = R[2]*gx + R[5]*gy + R[8]*gz;
        fr[1536 + hh*24 + p*3 + 0] = f2b(o0);
        fr[1536 + hh*24 + p*3 + 1] = f2b(o1);
        fr[1536 + hh*24 + p*3 + 2] = f2b(o2);
        fr[1728 + hh*8 + p] = f2b(sqrtf(o0*o0 + o1*o1 + o2*o2 + 1e-8f));
    }
}

// ---------------------------------------------------------------- launch ----
extern "C" void kernel_launch(void* const* d_in, const int* in_sizes, int n_in,
                              void* d_out, int out_size, void* d_ws, size_t ws_size,
                              hipStream_t stream) {
    const float* local      = (const float*)d_in[0];
    const float* pos        = (const float*)d_in[1];
    float*       pair       = (float*)d_in[2];    // feats written into it post-read
    const int*   neighbours = (const int*)d_in[4];
    const float* ln_s   = (const float*)d_in[9];
    const float* ln_b   = (const float*)d_in[10];
    const float* W_qkv  = (const float*)d_in[11];
    const float* ln_q_s = (const float*)d_in[12];
    const float* ln_q_b = (const float*)d_in[13];
    const float* ln_k_s = (const float*)d_in[14];
    const float* ln_k_b = (const float*)d_in[15];
    const float* W_pts  = (const float*)d_in[16];
    const float* W_bias = (const float*)d_in[17];
    const float* gamma  = (const float*)d_in[18];
    const float* W_out  = (const float*)d_in[19];
    const float* b_out  = (const float*)d_in[20];
    float* out = (float*)d_out;

    // ws: 44,498,944 bytes (round-3 footprint). Transposed bf16 weights
    // overlap dead regions (stream-ordered, safe):
    //   wt1 (W_qkv^T, 2.36MB) -> pts region (pts written later)
    //   wt2 (W_pts^T, 0.98MB) -> d_out      (d_out written only by final GEMM)
    //   wt3 (W_out^T, 2.75MB) -> pts region (pts dead after attn)
    float* Rm   = (float*)d_ws;                      // N*9
    float* tv   = Rm   + (size_t)NN * 9;             // N*3
    float* stat = tv   + (size_t)NN * 3;             // N*2
    float* pts  = stat + (size_t)NN * 2;             // N*576 fp32
    bf16*  qkv  = (bf16*)(pts + (size_t)NN * PTSD);  // N*1536 bf16 (last)
    bf16*  wt1  = (bf16*)pts;
    bf16*  wt2  = (bf16*)d_out;
    bf16*  wt3  = (bf16*)pts;

    frames_kernel<<<NN / 256, 256, 0, stream>>>(pos, Rm, tv);
    rowstat_kernel<<<NN, 256, 0, stream>>>(local, stat);

    // qkv = LN(local) @ W_qkv  (bf16 ws out; columns permuted q|k|v segregated)
    transpose_kernel<<<dim3(1536 / 32, 768 / 32), 256, 0, stream>>>(
        W_qkv, wt1, 768, 1536, 192, 64, 512);
    mfma_gemm<1, 0, 0><<<dim3(1536 / 128, NN / 128), 256, 0, stream>>>(
        local, DD, stat, ln_s, ln_b, wt1, qkv, QKVD, QKVD, nullptr, DD);
    ln_qk_kernel<<<(NN * HH) / 4, 256, 0, stream>>>(qkv, ln_q_s, ln_q_b, ln_k_s, ln_k_b);

    // pts_raw = LN(local) @ W_pts  (fp32 out; cols permuted qg|kg|vg; padded 640)
    transpose_kernel<<<dim3(640 / 32, 768 / 32), 256, 0, stream>>>(
        W_pts, wt2, 768, PTSD, 72, 24, 192);
    mfma_gemm<1, 1, 0><<<dim3(5, NN / 128), 256, 0, stream>>>(
        local, DD, stat, ln_s, ln_b, wt2, pts, PTSD, PTSD, nullptr, DD);
    rotate_pts_kernel<<<(NN * 192) / 256, 256, 0, stream>>>(pts, Rm, tv);

    attn_kernel<<<NN, 256, 0, stream>>>(qkv, pts, Rm, tv, pair, neighbours,
                                        W_bias, gamma);

    // out = feats @ W_out + b_out  (feats bf16 rows in pair buffer, pitch
    // 8192 bf16 elems; pts dead now -> wt3 reuses its space; fp32 out+bias)
    transpose_kernel<<<dim3(768 / 32, 1792 / 32), 256, 0, stream>>>(
        W_out, wt3, FEATD, DD, 0, 0, 0);
    mfma_gemm<0, 1, 1><<<dim3(768 / 128, NN / 128), 256, 0, stream>>>(
        pair, PAIR_ROW * 2, nullptr, nullptr, nullptr, wt3, out, DD, DD, b_out, FEATD);
}

// Round 3
// 526.625 us; speedup vs baseline: 1.2640x; 1.0508x over previous
//
#include <hip/hip_runtime.h>
#include <hip/hip_bf16.h>

// All float inputs/outputs are FP32. bf16 only for MFMA operands/intermediates.

#define NN 8192
#define KNBR 32
#define DD 768
#define CPC 128
#define HH 8
#define FEATD 1792
#define QKVD 1536
#define PTSD 576      // H * 24 * 3
#define PAIR_ROW 4096 // K*CP fp32 elements per residue row of `pair`

typedef __hip_bfloat16 bf16;
typedef __attribute__((ext_vector_type(8))) short s8;   // 8 bf16 (4 VGPRs)
typedef __attribute__((ext_vector_type(4))) float f4;   // MFMA accumulator
typedef __attribute__((ext_vector_type(4))) float fv4;  // ext-vector float4

__device__ __forceinline__ float b2f(bf16 v) { return __bfloat162float(v); }
__device__ __forceinline__ bf16 f2b(float v) { return __float2bfloat16(v); }
__device__ __forceinline__ unsigned short f2u(float v) {
    bf16 h = __float2bfloat16(v);
    return *(unsigned short*)&h;
}
// async global->LDS DMA, 16B per lane, wave-uniform LDS base (m97 recipe)
__device__ __forceinline__ void gl_lds16(const void* g, void* l) {
    __builtin_amdgcn_global_load_lds(
        (const __attribute__((address_space(1))) void*)g,
        (__attribute__((address_space(3))) void*)l, 16, 0, 0);
}

// ---------------------------------------------------------------- frames ----
__global__ __launch_bounds__(256) void frames_kernel(const float* __restrict__ pos,
                                                     float* __restrict__ Rm,
                                                     float* __restrict__ tv) {
    int n = blockIdx.x * blockDim.x + threadIdx.x;
    if (n >= NN) return;
    const float* p = pos + (size_t)n * 42;  // (14,3): N, CA, C first three
    float nx[3], ca[3], cc[3];
#pragma unroll
    for (int j = 0; j < 3; ++j) { nx[j] = p[j]; ca[j] = p[3+j]; cc[j] = p[6+j]; }
    float v1[3], v2[3], e1[3], e2[3], e3[3];
#pragma unroll
    for (int j = 0; j < 3; ++j) { v1[j] = cc[j] - ca[j]; v2[j] = nx[j] - ca[j]; }
    float s1 = v1[0]*v1[0] + v1[1]*v1[1] + v1[2]*v1[2];
    float r1 = 1.0f / sqrtf(s1 + 1e-8f);
#pragma unroll
    for (int j = 0; j < 3; ++j) e1[j] = v1[j] * r1;
    float d = v2[0]*e1[0] + v2[1]*e1[1] + v2[2]*e1[2];
    float u2[3];
#pragma unroll
    for (int j = 0; j < 3; ++j) u2[j] = v2[j] - d * e1[j];
    float s2 = u2[0]*u2[0] + u2[1]*u2[1] + u2[2]*u2[2];
    float r2 = 1.0f / sqrtf(s2 + 1e-8f);
#pragma unroll
    for (int j = 0; j < 3; ++j) e2[j] = u2[j] * r2;
    e3[0] = e1[1]*e2[2] - e1[2]*e2[1];
    e3[1] = e1[2]*e2[0] - e1[0]*e2[2];
    e3[2] = e1[0]*e2[1] - e1[1]*e2[0];
#pragma unroll
    for (int i = 0; i < 3; ++i) {
        Rm[(size_t)n*9 + i*3 + 0] = e1[i];
        Rm[(size_t)n*9 + i*3 + 1] = e2[i];
        Rm[(size_t)n*9 + i*3 + 2] = e3[i];
        tv[(size_t)n*3 + i] = ca[i];
    }
}

// --------------------------------------------- LN(local) -> xln (bf16) ------
__global__ __launch_bounds__(256) void ln_apply_kernel(const float* __restrict__ local,
                                                       const float* __restrict__ lns,
                                                       const float* __restrict__ lnb,
                                                       bf16* __restrict__ xln) {
    int n = blockIdx.x, tid = threadIdx.x;
    const float* row = local + (size_t)n * DD;
    float v[3];
#pragma unroll
    for (int e = 0; e < 3; ++e) v[e] = row[tid + 256*e];
    __shared__ float red[256];
    red[tid] = v[0] + v[1] + v[2];
    __syncthreads();
    for (int st = 128; st > 0; st >>= 1) {
        if (tid < st) red[tid] += red[tid + st];
        __syncthreads();
    }
    float mean = red[0] * (1.0f / DD);
    __syncthreads();
    float d0 = v[0]-mean, d1 = v[1]-mean, d2 = v[2]-mean;
    red[tid] = d0*d0 + d1*d1 + d2*d2;
    __syncthreads();
    for (int st = 128; st > 0; st >>= 1) {
        if (tid < st) red[tid] += red[tid + st];
        __syncthreads();
    }
    float rstd = rsqrtf(red[0] * (1.0f / DD) + 1e-5f);
    bf16* orow = xln + (size_t)n * DD;
#pragma unroll
    for (int e = 0; e < 3; ++e) {
        int c = tid + 256*e;
        orow[c] = f2b((v[e] - mean) * rstd * lns[c] + lnb[c]);
    }
}

// ----------------------------------------------------- weight transpose -----
// W: K x N (row-major FP32) -> Wt: (rowoff + Npad) x K (row-major bf16),
// zero rows for n >= N. Optional output-row permutation (cn != 0):
// old col = h*group + seg*cn + c -> row rowoff + seg*segsz + h*cn + c.
__global__ __launch_bounds__(256) void transpose_kernel(const float* __restrict__ W,
                                                        bf16* __restrict__ Wt,
                                                        int K, int N,
                                                        int group, int cn, int segsz,
                                                        int rowoff) {
    __shared__ bf16 tile[32][33];
    int n0 = blockIdx.x * 32, k0 = blockIdx.y * 32;
    int tid = threadIdx.x;
    int r = tid >> 5, c = tid & 31;
    for (int rr = r; rr < 32; rr += 8) {
        int n = n0 + c;
        tile[rr][c] = (n < N) ? f2b(W[(size_t)(k0 + rr) * N + n]) : f2b(0.0f);
    }
    __syncthreads();
    for (int rr = r; rr < 32; rr += 8) {
        int n = n0 + rr;
        int pn = n;
        if (cn != 0 && n < N) {
            int hh = n / group, rm = n % group;
            pn = (rm / cn) * segsz + hh * cn + (rm % cn);
        }
        Wt[(size_t)(rowoff + pn) * K + k0 + c] = tile[c][rr];
    }
}

// ------------------------------------------------------------ MFMA GEMM -----
// C = A[M x K](bf16) @ Bt^T (Bt stored N x K bf16, pre-transposed).
// 128x128 tile, BK=32, 4 waves x (4x4) mfma_f32_16x16x32_bf16.
// Staging via global_load_lds dwordx4 (wave-uniform LDS base + lane*16B):
// each wave DMAs 2x1KB chunks of A and of B per K-step (m97 structure).
// SPLIT=0: fp32 C (+bias if BIAS) with ncols guard.
// SPLIT=1: cols <  QKVD -> bf16 into C (ldc QKVD);
//          cols >= QKVD -> fp32 into C2 (ldc PTSD, guard col-QKVD < PTSD).
template<int SPLIT, int BIAS>
__global__ __launch_bounds__(256) void mfma_gemm(const bf16* __restrict__ A, int lda,
                                                 const bf16* __restrict__ Bt, int K,
                                                 void* __restrict__ C,
                                                 void* __restrict__ C2,
                                                 int ldc, int ncols,
                                                 const float* __restrict__ bias) {
    __shared__ short As[128 * 32];   // [row][k] bf16 bits, 8 KB
    __shared__ short Bs[128 * 32];   // [n][k]  bf16 bits, 8 KB
    int tid = threadIdx.x;
    int w = tid >> 6, lane = tid & 63;
    int q = lane >> 4, lr = lane & 15;
    int m0 = blockIdx.y * 128, n0 = blockIdx.x * 128;
    int lrow = lane >> 2, lcol = (lane & 3) * 8;   // DMA lane mapping

    f4 acc[4][4] = {};

    for (int k0 = 0; k0 < K; k0 += 32) {
        // ---- stage A+B tiles: 8 chunks each of 16 rows (1KB); wave w does
        //      chunks 2w, 2w+1 of both tiles ----
#pragma unroll
        for (int i = 0; i < 2; ++i) {
            int c = w * 2 + i;
            int r = c * 16 + lrow;
            gl_lds16(A  + (size_t)(m0 + r) * lda + k0 + lcol, As + c * 512);
            gl_lds16(Bt + (size_t)(n0 + r) * K   + k0 + lcol, Bs + c * 512);
        }
        __syncthreads();   // drains vmcnt(0): DMA complete for all waves

        // ---- fragments + 16 MFMAs ----
        const short* Ab = As + ((w & 1) * 64 + lr) * 32 + q * 8;
        const short* Bb = Bs + ((w >> 1) * 64 + lr) * 32 + q * 8;
        s8 af[4], bfr[4];
#pragma unroll
        for (int i = 0; i < 4; ++i) af[i] = *(const s8*)(Ab + i * 16 * 32);
#pragma unroll
        for (int j = 0; j < 4; ++j) bfr[j] = *(const s8*)(Bb + j * 16 * 32);
#pragma unroll
        for (int i = 0; i < 4; ++i)
#pragma unroll
            for (int j = 0; j < 4; ++j)
                acc[i][j] = __builtin_amdgcn_mfma_f32_16x16x32_bf16(
                    af[i], bfr[j], acc[i][j], 0, 0, 0);
        __syncthreads();
    }

    // ---- epilogue: C/D layout col=lane&15, row=(lane>>4)*4+reg ----
    int mb = m0 + (w & 1) * 64, nb = n0 + (w >> 1) * 64;
#pragma unroll
    for (int i = 0; i < 4; ++i) {
#pragma unroll
        for (int j = 0; j < 4; ++j) {
            int col = nb + j * 16 + lr;
            int row0 = mb + i * 16 + q * 4;
            if (!SPLIT) {
                if (col < ncols) {
#pragma unroll
                    for (int r = 0; r < 4; ++r) {
                        float v = acc[i][j][r];
                        if (BIAS) v += bias[col];
                        ((float*)C)[(size_t)(row0 + r) * ldc + col] = v;
                    }
                }
            } else {
                if (col < QKVD) {
#pragma unroll
                    for (int r = 0; r < 4; ++r)
                        ((unsigned short*)C)[(size_t)(row0 + r) * QKVD + col] =
                            f2u(acc[i][j][r]);
                } else if (col - QKVD < PTSD) {
                    int pc = col - QKVD;
#pragma unroll
                    for (int r = 0; r < 4; ++r)
                        ((float*)C2)[(size_t)(row0 + r) * PTSD + pc] = acc[i][j][r];
                }
            }
        }
    }
}

// --------------------------------------------------------- per-head LN q,k --
// qkv layout segregated: q at [0,512), k at [512,1024), v at [1024,1536)
// with per-head 64-wide slices (h*64+c) in each segment.
__global__ __launch_bounds__(256) void ln_qk_kernel(bf16* __restrict__ qkv,
                                                    const float* __restrict__ qs,
                                                    const float* __restrict__ qb,
                                                    const float* __restrict__ ks,
                                                    const float* __restrict__ kb) {
    int tid = threadIdx.x;
    int pi = blockIdx.x * 4 + (tid >> 6);  // (n,h) pair index
    int lane = tid & 63;
    bf16* base = qkv + (size_t)(pi >> 3) * QKVD + (pi & 7) * 64;
#pragma unroll
    for (int part = 0; part < 2; ++part) {
        int off = part * 512;
        const float* sc = part ? ks : qs;
        const float* of = part ? kb : qb;
        float v = b2f(base[off + lane]);
        float s = v;
#pragma unroll
        for (int m = 32; m > 0; m >>= 1) s += __shfl_xor(s, m, 64);
        float mean = s * (1.0f / 64.0f);
        float d = v - mean;
        float sq = d * d;
#pragma unroll
        for (int m = 32; m > 0; m >>= 1) sq += __shfl_xor(sq, m, 64);
        float inv = rsqrtf(sq * (1.0f / 64.0f) + 1e-5f);
        base[off + lane] = f2b(d * inv * sc[lane] + of[lane]);
    }
}

// -------------------------------------------------------- rotate points -----
__global__ __launch_bounds__(256) void rotate_pts_kernel(float* __restrict__ pts,
                                                         const float* __restrict__ Rm,
                                                         const float* __restrict__ tv) {
    int idx = blockIdx.x * blockDim.x + threadIdx.x;  // over N*192
    if (idx >= NN * 192) return;
    int n = idx / 192;
    int rem = idx % 192;
    float* base = pts + (size_t)n * PTSD + rem * 3;
    float r0 = base[0], r1 = base[1], r2 = base[2];
    const float* R = Rm + (size_t)n * 9;
    const float* t = tv + (size_t)n * 3;
    base[0] = R[0]*r0 + R[1]*r1 + R[2]*r2 + t[0];
    base[1] = R[3]*r0 + R[4]*r1 + R[5]*r2 + t[1];
    base[2] = R[6]*r0 + R[7]*r1 + R[8]*r2 + t[2];
}

// ------------------------------------------------------------- attention ----
// Segregated layouts:
//   qkv row: [q: h*64+c | 512 + k: h*64+c | 1024 + v: h*64+c]
//   pts row: [qg: h*24+e | 192 + kg: h*24+e | 384 + vg: h*24+e]  (e = p*3+d)
__global__ __launch_bounds__(256) void attn_kernel(const bf16* __restrict__ qkv,
                                                   const float* __restrict__ pts,
                                                   const float* __restrict__ Rm,
                                                   const float* __restrict__ tv,
                                                   float* __restrict__ pair,
                                                   const int* __restrict__ nbr,
                                                   const float* __restrict__ Wb,
                                                   const float* __restrict__ gamma) {
    int n = blockIdx.x;
    int tid = threadIdx.x;
    int w = tid >> 6, lane = tid & 63;
    int h = lane >> 3, cg = lane & 7;

    __shared__ float pairS[32][132];  // pad 132: float4-aligned, conflict-free
    __shared__ float logitS[32][8];
    __shared__ float attnS[32][8];
    __shared__ float gS[192];
    __shared__ int nbS[32];
    __shared__ float dfS[8];

    // ---- stage pair row (nontemporal: evict-first, keep L3 for gathers) ----
    const fv4* pr4 = (const fv4*)(pair + (size_t)n * PAIR_ROW);
    for (int e = tid; e < 1024; e += 256) {
        fv4 u = __builtin_nontemporal_load(pr4 + e);
        int k = e >> 5, c0 = (e & 31) * 4;
        *(fv4*)&pairS[k][c0] = u;
    }
    if (tid < 32) nbS[tid] = nbr[(size_t)n * KNBR + tid];
    if (tid < 8) dfS[tid] = log1pf(expf(gamma[tid])) * (1.0f / 12.0f);

    // ---- hoist loop-invariants into registers ----
    float qreg[8];
    {
        uint4 qv = *(const uint4*)(qkv + (size_t)n * QKVD + h * 64 + cg * 8);
        const unsigned short* qs = (const unsigned short*)&qv;
#pragma unroll
        for (int j = 0; j < 8; ++j) qreg[j] = b2f(*(const bf16*)&qs[j]);
    }
    fv4 qg = (fv4)(0.0f);
    if (cg < 6) qg = *(const fv4*)(pts + (size_t)n * PTSD + h * 24 + cg * 4);
    float wb[16];
#pragma unroll
    for (int j = 0; j < 16; ++j) wb[j] = Wb[(cg + 8 * j) * 8 + h];  // Wb 4KB, hot

    __syncthreads();

    // ---- logits: wave w owns k = w*8 .. w*8+7 ----
#pragma unroll
    for (int kk = 0; kk < 8; ++kk) {
        int k = w * 8 + kk;
        int nb = nbS[k];
        uint4 kv = *(const uint4*)(qkv + (size_t)nb * QKVD + 512 + h * 64 + cg * 8);
        const unsigned short* ks = (const unsigned short*)&kv;
        float dot = 0.0f;
#pragma unroll
        for (int j = 0; j < 8; ++j) dot += qreg[j] * b2f(*(const bf16*)&ks[j]);
        float d2 = 0.0f;
        if (cg < 6) {
            fv4 kg = *(const fv4*)(pts + (size_t)nb * PTSD + 192 + h * 24 + cg * 4);
            float dx = qg.x - kg.x, dy = qg.y - kg.y, dz = qg.z - kg.z, dw = qg.w - kg.w;
            d2 = dx*dx + dy*dy + dz*dz + dw*dw;
        }
        float bias = 0.0f;
#pragma unroll
        for (int j = 0; j < 16; ++j) bias += pairS[k][cg + 8 * j] * wb[j];

        float val = 0.125f * dot + bias - dfS[h] * d2;
        val += __shfl_xor(val, 1, 64);
        val += __shfl_xor(val, 2, 64);
        val += __shfl_xor(val, 4, 64);
        if (cg == 0) logitS[k][h] = 0.5773502691896258f * val;
    }
    __syncthreads();

    // ---- softmax over k, one wave: lane = h*8 + j, j owns k = j + 8i ----
    if (tid < 64) {
        int hh = tid >> 3, j = tid & 7;
        float l[4];
        float m = -1e30f;
#pragma unroll
        for (int i = 0; i < 4; ++i) { l[i] = logitS[j + 8 * i][hh]; m = fmaxf(m, l[i]); }
        m = fmaxf(m, __shfl_xor(m, 1, 64));
        m = fmaxf(m, __shfl_xor(m, 2, 64));
        m = fmaxf(m, __shfl_xor(m, 4, 64));
        float s = 0.0f;
#pragma unroll
        for (int i = 0; i < 4; ++i) { l[i] = expf(l[i] - m); s += l[i]; }
        s += __shfl_xor(s, 1, 64);
        s += __shfl_xor(s, 2, 64);
        s += __shfl_xor(s, 4, 64);
        float inv = 1.0f / s;
#pragma unroll
        for (int i = 0; i < 4; ++i) attnS[j + 8 * i][hh] = l[i] * inv;
    }
    __syncthreads();

    bf16* fr = (bf16*)(pair + (size_t)n * PAIR_ROW);  // feats row
    // ---- out_pair: 1024 = H*CP ----
    for (int e = tid; e < 1024; e += 256) {
        int hh = e >> 7, c = e & 127;
        float acc = 0.0f;
#pragma unroll
        for (int k = 0; k < KNBR; ++k) acc += attnS[k][hh] * pairS[k][c];
        fr[e] = f2b(acc);
    }
    // ---- out_scalar: 512 = H*S (coalesced v gathers) ----
    for (int e = tid; e < 512; e += 256) {
        int hh = e >> 6, c = e & 63;
        float acc = 0.0f;
#pragma unroll
        for (int k = 0; k < KNBR; ++k)
            acc += attnS[k][hh] * b2f(qkv[(size_t)nbS[k] * QKVD + 1024 + hh * 64 + c]);
        fr[1024 + e] = f2b(acc);
    }
    // ---- op: 192 threads, coalesced per-k v_g rows ----
    if (tid < 192) {
        int hh = tid / 24;
        float acc = 0.0f;
#pragma unroll
        for (int k = 0; k < KNBR; ++k)
            acc += attnS[k][hh] * pts[(size_t)nbS[k] * PTSD + 384 + tid];
        gS[tid] = acc;
    }
    __syncthreads();
    if (tid < 64) {
        int hh = tid >> 3, p = tid & 7;
        const float* t = tv + (size_t)n * 3;
        const float* R = Rm + (size_t)n * 9;
        float gx = gS[hh * 24 + p * 3 + 0] - t[0];
        float gy = gS[hh * 24 + p * 3 + 1] - t[1];
        float gz = gS[hh * 24 + p * 3 + 2] - t[2];
        // einsum('nji,...j->...i') = R^T g
        float o0 = R[0]*gx + R[3]*gy + R[6]*gz;
        float o1 = R[1]*gx + R[4]*gy + R[7]*gz;
        float o2 = R[2]*gx + R[5]*gy + R[8]*gz;
        fr[1536 + hh*24 + p*3 + 0] = f2b(o0);
        fr[1536 + hh*24 + p*3 + 1] = f2b(o1);
        fr[1536 + hh*24 + p*3 + 2] = f2b(o2);
        fr[1728 + hh*8 + p] = f2b(sqrtf(o0*o0 + o1*o1 + o2*o2 + 1e-8f));
    }
}

// ---------------------------------------------------------------- launch ----
extern "C" void kernel_launch(void* const* d_in, const int* in_sizes, int n_in,
                              void* d_out, int out_size, void* d_ws, size_t ws_size,
                              hipStream_t stream) {
    const float* local      = (const float*)d_in[0];
    const float* pos        = (const float*)d_in[1];
    float*       pair       = (float*)d_in[2];    // feats written into it post-read
    const int*   neighbours = (const int*)d_in[4];
    const float* ln_s   = (const float*)d_in[9];
    const float* ln_b   = (const float*)d_in[10];
    const float* W_qkv  = (const float*)d_in[11];
    const float* ln_q_s = (const float*)d_in[12];
    const float* ln_q_b = (const float*)d_in[13];
    const float* ln_k_s = (const float*)d_in[14];
    const float* ln_k_b = (const float*)d_in[15];
    const float* W_pts  = (const float*)d_in[16];
    const float* W_bias = (const float*)d_in[17];
    const float* gamma  = (const float*)d_in[18];
    const float* W_out  = (const float*)d_in[19];
    const float* b_out  = (const float*)d_in[20];
    float* out = (float*)d_out;

    // ws (44,498,944 B): Rm | tv | pts | qkv.
    // d_out (25.17 MB) hosts xln (12.58 MB) + wtm (3.34 MB) until final GEMM:
    // both are dead before the final GEMM writes d_out (stream-ordered, safe).
    // wt3 (W_out^T, 2.75 MB) reuses pts region (pts dead after attn).
    float* Rm   = (float*)d_ws;                      // N*9
    float* tv   = Rm   + (size_t)NN * 9;             // N*3
    float* pts  = tv   + (size_t)NN * 3;             // N*576 fp32
    bf16*  qkv  = (bf16*)(pts + (size_t)NN * PTSD);  // N*1536 bf16
    bf16*  xln  = (bf16*)d_out;                      // N*768 bf16
    bf16*  wtm  = xln + (size_t)NN * DD;             // 2176*768 bf16
    bf16*  wt3  = (bf16*)pts;                        // 768*1792 bf16 (post-attn)

    frames_kernel<<<NN / 256, 256, 0, stream>>>(pos, Rm, tv);
    ln_apply_kernel<<<NN, 256, 0, stream>>>(local, ln_s, ln_b, xln);

    // merged weights: W_qkv^T (perm q|k|v) rows 0..1535,
    //                 W_pts^T (perm qg|kg|vg, zero-pad to 640) rows 1536..2175
    transpose_kernel<<<dim3(1536 / 32, 768 / 32), 256, 0, stream>>>(
        W_qkv, wtm, 768, 1536, 192, 64, 512, 0);
    transpose_kernel<<<dim3(640 / 32, 768 / 32), 256, 0, stream>>>(
        W_pts, wtm, 768, PTSD, 72, 24, 192, 1536);

    // [qkv | pts_raw] = xln @ wtm^T  (split epilogue: bf16 qkv / fp32 pts)
    mfma_gemm<1, 0><<<dim3(2176 / 128, NN / 128), 256, 0, stream>>>(
        xln, DD, wtm, DD, qkv, pts, 0, 2176, nullptr);

    ln_qk_kernel<<<(NN * HH) / 4, 256, 0, stream>>>(qkv, ln_q_s, ln_q_b, ln_k_s, ln_k_b);
    rotate_pts_kernel<<<(NN * 192) / 256, 256, 0, stream>>>(pts, Rm, tv);

    attn_kernel<<<NN, 256, 0, stream>>>(qkv, pts, Rm, tv, pair, neighbours,
                                        W_bias, gamma);

    // out = feats @ W_out + b_out  (feats bf16 rows in pair buffer, pitch
    // 8192 bf16 elems; pts dead now -> wt3 reuses its space; fp32 out+bias)
    transpose_kernel<<<dim3(768 / 32, 1792 / 32), 256, 0, stream>>>(
        W_out, wt3, FEATD, DD, 0, 0, 0, 0);
    mfma_gemm<0, 1><<<dim3(768 / 128, NN / 128), 256, 0, stream>>>(
        (const bf16*)pair, PAIR_ROW * 2, wt3, FEATD, out, nullptr, DD, DD, b_out);
}

// Round 4
// 500.346 us; speedup vs baseline: 1.3304x; 1.0525x over previous
//
#include <hip/hip_runtime.h>
#include <hip/hip_bf16.h>

// All float inputs/outputs are FP32. bf16 only for MFMA operands/intermediates.

#define NN 8192
#define KNBR 32
#define DD 768
#define CPC 128
#define HH 8
#define FEATD 1792
#define QKVD 1536
#define PTSD 576      // H * 24 * 3
#define PAIR_ROW 4096 // K*CP fp32 elements per residue row of `pair`

typedef __hip_bfloat16 bf16;
typedef __attribute__((ext_vector_type(8))) short s8;   // 8 bf16 (4 VGPRs)
typedef __attribute__((ext_vector_type(4))) float f4;   // MFMA accumulator
typedef __attribute__((ext_vector_type(4))) float fv4;  // ext-vector float4

__device__ __forceinline__ float b2f(bf16 v) { return __bfloat162float(v); }
__device__ __forceinline__ bf16 f2b(float v) { return __float2bfloat16(v); }
__device__ __forceinline__ unsigned short f2u(float v) {
    bf16 h = __float2bfloat16(v);
    return *(unsigned short*)&h;
}
// async global->LDS DMA, 16B per lane, wave-uniform LDS base (m97 recipe)
__device__ __forceinline__ void gl_lds16(const void* g, void* l) {
    __builtin_amdgcn_global_load_lds(
        (const __attribute__((address_space(1))) void*)g,
        (__attribute__((address_space(3))) void*)l, 16, 0, 0);
}

// ---------------------------------------------------------- device: frames --
__device__ __forceinline__ void do_frames(int n, const float* __restrict__ pos,
                                          float* __restrict__ Rm,
                                          float* __restrict__ tv) {
    const float* p = pos + (size_t)n * 42;  // (14,3): N, CA, C first three
    float nx[3], ca[3], cc[3];
#pragma unroll
    for (int j = 0; j < 3; ++j) { nx[j] = p[j]; ca[j] = p[3+j]; cc[j] = p[6+j]; }
    float v1[3], v2[3], e1[3], e2[3], e3[3];
#pragma unroll
    for (int j = 0; j < 3; ++j) { v1[j] = cc[j] - ca[j]; v2[j] = nx[j] - ca[j]; }
    float s1 = v1[0]*v1[0] + v1[1]*v1[1] + v1[2]*v1[2];
    float r1 = 1.0f / sqrtf(s1 + 1e-8f);
#pragma unroll
    for (int j = 0; j < 3; ++j) e1[j] = v1[j] * r1;
    float d = v2[0]*e1[0] + v2[1]*e1[1] + v2[2]*e1[2];
    float u2[3];
#pragma unroll
    for (int j = 0; j < 3; ++j) u2[j] = v2[j] - d * e1[j];
    float s2 = u2[0]*u2[0] + u2[1]*u2[1] + u2[2]*u2[2];
    float r2 = 1.0f / sqrtf(s2 + 1e-8f);
#pragma unroll
    for (int j = 0; j < 3; ++j) e2[j] = u2[j] * r2;
    e3[0] = e1[1]*e2[2] - e1[2]*e2[1];
    e3[1] = e1[2]*e2[0] - e1[0]*e2[2];
    e3[2] = e1[0]*e2[1] - e1[1]*e2[0];
#pragma unroll
    for (int i = 0; i < 3; ++i) {
        Rm[(size_t)n*9 + i*3 + 0] = e1[i];
        Rm[(size_t)n*9 + i*3 + 1] = e2[i];
        Rm[(size_t)n*9 + i*3 + 2] = e3[i];
        tv[(size_t)n*3 + i] = ca[i];
    }
}

// ------------------------------------------------------- device: transpose --
// W: K x N (fp32) -> Wt: (rowoff+Npad) x K (bf16), zero rows >= N.
// cn != 0: head-segregation perm, old col h*group+seg*cn+c -> seg*segsz+h*cn+c.
__device__ __forceinline__ void do_transpose(const float* __restrict__ W,
                                             bf16* __restrict__ Wt,
                                             int K, int N, int group, int cn,
                                             int segsz, int rowoff,
                                             int bx, int by, int tid,
                                             char* shbuf) {
    bf16 (*tile)[33] = (bf16(*)[33])shbuf;  // 2112 B
    int n0 = bx * 32, k0 = by * 32;
    int r = tid >> 5, c = tid & 31;
    for (int rr = r; rr < 32; rr += 8) {
        int n = n0 + c;
        tile[rr][c] = (n < N) ? f2b(W[(size_t)(k0 + rr) * N + n]) : f2b(0.0f);
    }
    __syncthreads();
    for (int rr = r; rr < 32; rr += 8) {
        int n = n0 + rr;
        int pn = n;
        if (cn != 0 && n < N) {
            int hh = n / group, rm = n % group;
            pn = (rm / cn) * segsz + hh * cn + (rm % cn);
        }
        Wt[(size_t)(rowoff + pn) * K + k0 + c] = tile[c][rr];
    }
}

// ------------------------------------------------------------------- prep ----
// blocks [0,NN): LN(local) row b -> xln bf16 (+ frames for b<32, 1 res/thread)
// blocks [NN, NN+1152): transpose W_qkv -> wtm rows 0..1535 (q|k|v perm)
// blocks [NN+1152, NN+1632): transpose W_pts -> wtm rows 1536..2175 (perm, pad)
__global__ __launch_bounds__(256) void prep_kernel(
        const float* __restrict__ local, const float* __restrict__ lns,
        const float* __restrict__ lnb, bf16* __restrict__ xln,
        const float* __restrict__ pos, float* __restrict__ Rm,
        float* __restrict__ tv,
        const float* __restrict__ W_qkv, const float* __restrict__ W_pts,
        bf16* __restrict__ wtm) {
    __shared__ __align__(16) char shbuf[2560];
    int b = blockIdx.x, tid = threadIdx.x;
    if (b < NN) {
        if (b < 32) do_frames(b * 256 + tid, pos, Rm, tv);
        float* red = (float*)shbuf;
        const float* row = local + (size_t)b * DD;
        float v[3];
#pragma unroll
        for (int e = 0; e < 3; ++e) v[e] = row[tid + 256*e];
        red[tid] = v[0] + v[1] + v[2];
        __syncthreads();
        for (int st = 128; st > 0; st >>= 1) {
            if (tid < st) red[tid] += red[tid + st];
            __syncthreads();
        }
        float mean = red[0] * (1.0f / DD);
        __syncthreads();
        float d0 = v[0]-mean, d1 = v[1]-mean, d2 = v[2]-mean;
        red[tid] = d0*d0 + d1*d1 + d2*d2;
        __syncthreads();
        for (int st = 128; st > 0; st >>= 1) {
            if (tid < st) red[tid] += red[tid + st];
            __syncthreads();
        }
        float rstd = rsqrtf(red[0] * (1.0f / DD) + 1e-5f);
        bf16* orow = xln + (size_t)b * DD;
#pragma unroll
        for (int e = 0; e < 3; ++e) {
            int c = tid + 256*e;
            orow[c] = f2b((v[e] - mean) * rstd * lns[c] + lnb[c]);
        }
    } else if (b < NN + 1152) {
        int t = b - NN;
        do_transpose(W_qkv, wtm, 768, 1536, 192, 64, 512, 0, t % 48, t / 48,
                     tid, shbuf);
    } else {
        int t = b - NN - 1152;
        do_transpose(W_pts, wtm, 768, PTSD, 72, 24, 192, 1536, t % 20, t / 20,
                     tid, shbuf);
    }
}

// ----------------------------------------------------- weight transpose -----
// standalone (wt3 must wait until pts region is dead, post-attn)
__global__ __launch_bounds__(256) void transpose_kernel(const float* __restrict__ W,
                                                        bf16* __restrict__ Wt,
                                                        int K, int N,
                                                        int group, int cn, int segsz,
                                                        int rowoff) {
    __shared__ __align__(16) char shbuf[2560];
    do_transpose(W, Wt, K, N, group, cn, segsz, rowoff,
                 blockIdx.x, blockIdx.y, threadIdx.x, shbuf);
}

// ------------------------------------------------------------ MFMA GEMM -----
// C = A[M x K](bf16) @ Bt^T (Bt stored N x K bf16, pre-transposed).
// 128x128 tile, BK=32, 4 waves x (4x4) mfma_f32_16x16x32_bf16,
// global_load_lds dwordx4 staging (m97 structure).
// SPLIT=0: fp32 C (+bias if BIAS) with ncols guard.
// SPLIT=1: cols <  1024 -> per-head LN(q/k) over the wave's 64-col slice
//                          (fp32 stats via shfl_xor over lr bits) -> bf16 C;
//          cols < QKVD   -> v passthrough bf16;
//          cols >= QKVD  -> fp32 into C2 (pts, guard col-QKVD < PTSD).
template<int SPLIT, int BIAS>
__global__ __launch_bounds__(256) void mfma_gemm(const bf16* __restrict__ A, int lda,
                                                 const bf16* __restrict__ Bt, int K,
                                                 void* __restrict__ C,
                                                 void* __restrict__ C2,
                                                 int ldc, int ncols,
                                                 const float* __restrict__ bias,
                                                 const float* __restrict__ lnqs,
                                                 const float* __restrict__ lnqb,
                                                 const float* __restrict__ lnks,
                                                 const float* __restrict__ lnkb) {
    __shared__ short As[128 * 32];   // [row][k] bf16 bits, 8 KB
    __shared__ short Bs[128 * 32];   // [n][k]  bf16 bits, 8 KB
    int tid = threadIdx.x;
    int w = tid >> 6, lane = tid & 63;
    int q = lane >> 4, lr = lane & 15;
    int m0 = blockIdx.y * 128, n0 = blockIdx.x * 128;
    int lrow = lane >> 2, lcol = (lane & 3) * 8;   // DMA lane mapping

    f4 acc[4][4] = {};

    for (int k0 = 0; k0 < K; k0 += 32) {
#pragma unroll
        for (int i = 0; i < 2; ++i) {
            int c = w * 2 + i;
            int r = c * 16 + lrow;
            gl_lds16(A  + (size_t)(m0 + r) * lda + k0 + lcol, As + c * 512);
            gl_lds16(Bt + (size_t)(n0 + r) * K   + k0 + lcol, Bs + c * 512);
        }
        __syncthreads();   // drains vmcnt(0): DMA complete for all waves

        const short* Ab = As + ((w & 1) * 64 + lr) * 32 + q * 8;
        const short* Bb = Bs + ((w >> 1) * 64 + lr) * 32 + q * 8;
        s8 af[4], bfr[4];
#pragma unroll
        for (int i = 0; i < 4; ++i) af[i] = *(const s8*)(Ab + i * 16 * 32);
#pragma unroll
        for (int j = 0; j < 4; ++j) bfr[j] = *(const s8*)(Bb + j * 16 * 32);
#pragma unroll
        for (int i = 0; i < 4; ++i)
#pragma unroll
            for (int j = 0; j < 4; ++j)
                acc[i][j] = __builtin_amdgcn_mfma_f32_16x16x32_bf16(
                    af[i], bfr[j], acc[i][j], 0, 0, 0);
        __syncthreads();
    }

    // ---- epilogue: C/D layout col=lane&15, row=(lane>>4)*4+reg ----
    int mb = m0 + (w & 1) * 64, nb = n0 + (w >> 1) * 64;
    if (!SPLIT) {
#pragma unroll
        for (int i = 0; i < 4; ++i)
#pragma unroll
            for (int j = 0; j < 4; ++j) {
                int col = nb + j * 16 + lr;
                int row0 = mb + i * 16 + q * 4;
                if (col < ncols) {
#pragma unroll
                    for (int r = 0; r < 4; ++r) {
                        float v = acc[i][j][r];
                        if (BIAS) v += bias[col];
                        ((float*)C)[(size_t)(row0 + r) * ldc + col] = v;
                    }
                }
            }
    } else if (nb < 1024) {
        // fused per-head LN over the wave's 64-col q/k slice (fp32 stats)
        const float* sc = (nb < 512) ? lnqs : lnks;
        const float* of = (nb < 512) ? lnqb : lnkb;
        float scv[4], ofv[4];
#pragma unroll
        for (int j = 0; j < 4; ++j) { scv[j] = sc[j*16 + lr]; ofv[j] = of[j*16 + lr]; }
#pragma unroll
        for (int i = 0; i < 4; ++i) {
#pragma unroll
            for (int r = 0; r < 4; ++r) {
                float s = acc[i][0][r] + acc[i][1][r] + acc[i][2][r] + acc[i][3][r];
                s += __shfl_xor(s, 1, 64); s += __shfl_xor(s, 2, 64);
                s += __shfl_xor(s, 4, 64); s += __shfl_xor(s, 8, 64);
                float mean = s * (1.0f / 64.0f);
                float d0 = acc[i][0][r] - mean, d1 = acc[i][1][r] - mean;
                float d2 = acc[i][2][r] - mean, d3 = acc[i][3][r] - mean;
                float vs = d0*d0 + d1*d1 + d2*d2 + d3*d3;
                vs += __shfl_xor(vs, 1, 64); vs += __shfl_xor(vs, 2, 64);
                vs += __shfl_xor(vs, 4, 64); vs += __shfl_xor(vs, 8, 64);
                float rstd = rsqrtf(vs * (1.0f / 64.0f) + 1e-5f);
                unsigned short* Crow =
                    (unsigned short*)C + (size_t)(mb + i*16 + q*4 + r) * QKVD + nb;
                Crow[0*16 + lr] = f2u(d0 * rstd * scv[0] + ofv[0]);
                Crow[1*16 + lr] = f2u(d1 * rstd * scv[1] + ofv[1]);
                Crow[2*16 + lr] = f2u(d2 * rstd * scv[2] + ofv[2]);
                Crow[3*16 + lr] = f2u(d3 * rstd * scv[3] + ofv[3]);
            }
        }
    } else if (nb < QKVD) {
        // v passthrough
#pragma unroll
        for (int i = 0; i < 4; ++i)
#pragma unroll
            for (int j = 0; j < 4; ++j) {
                int col = nb + j * 16 + lr;
                int row0 = mb + i * 16 + q * 4;
#pragma unroll
                for (int r = 0; r < 4; ++r)
                    ((unsigned short*)C)[(size_t)(row0 + r) * QKVD + col] =
                        f2u(acc[i][j][r]);
            }
    } else {
        // pts fp32
#pragma unroll
        for (int i = 0; i < 4; ++i)
#pragma unroll
            for (int j = 0; j < 4; ++j) {
                int col = nb + j * 16 + lr;
                int row0 = mb + i * 16 + q * 4;
                if (col - QKVD < PTSD) {
                    int pc = col - QKVD;
#pragma unroll
                    for (int r = 0; r < 4; ++r)
                        ((float*)C2)[(size_t)(row0 + r) * PTSD + pc] = acc[i][j][r];
                }
            }
    }
}

// -------------------------------------------------------- rotate points -----
__global__ __launch_bounds__(256) void rotate_pts_kernel(float* __restrict__ pts,
                                                         const float* __restrict__ Rm,
                                                         const float* __restrict__ tv) {
    int idx = blockIdx.x * blockDim.x + threadIdx.x;  // over N*192
    if (idx >= NN * 192) return;
    int n = idx / 192;
    int rem = idx % 192;
    float* base = pts + (size_t)n * PTSD + rem * 3;
    float r0 = base[0], r1 = base[1], r2 = base[2];
    const float* R = Rm + (size_t)n * 9;
    const float* t = tv + (size_t)n * 3;
    base[0] = R[0]*r0 + R[1]*r1 + R[2]*r2 + t[0];
    base[1] = R[3]*r0 + R[4]*r1 + R[5]*r2 + t[1];
    base[2] = R[6]*r0 + R[7]*r1 + R[8]*r2 + t[2];
}

// ------------------------------------------------------------- attention ----
// Segregated layouts:
//   qkv row: [q: h*64+c | 512 + k: h*64+c | 1024 + v: h*64+c]
//   pts row: [qg: h*24+e | 192 + kg: h*24+e | 384 + vg: h*24+e]  (e = p*3+d)
__global__ __launch_bounds__(256) void attn_kernel(const bf16* __restrict__ qkv,
                                                   const float* __restrict__ pts,
                                                   const float* __restrict__ Rm,
                                                   const float* __restrict__ tv,
                                                   float* __restrict__ pair,
                                                   const int* __restrict__ nbr,
                                                   const float* __restrict__ Wb,
                                                   const float* __restrict__ gamma) {
    int n = blockIdx.x;
    int tid = threadIdx.x;
    int w = tid >> 6, lane = tid & 63;
    int h = lane >> 3, cg = lane & 7;

    __shared__ float pairS[32][132];  // pad 132: float4-aligned, conflict-free
    __shared__ float logitS[32][8];
    __shared__ float attnS[32][8];
    __shared__ float gS[192];
    __shared__ int nbS[32];
    __shared__ float dfS[8];

    // ---- stage pair row (nontemporal: evict-first, keep L3 for gathers) ----
    const fv4* pr4 = (const fv4*)(pair + (size_t)n * PAIR_ROW);
    for (int e = tid; e < 1024; e += 256) {
        fv4 u = __builtin_nontemporal_load(pr4 + e);
        int k = e >> 5, c0 = (e & 31) * 4;
        *(fv4*)&pairS[k][c0] = u;
    }
    if (tid < 32) nbS[tid] = nbr[(size_t)n * KNBR + tid];
    if (tid < 8) dfS[tid] = log1pf(expf(gamma[tid])) * (1.0f / 12.0f);

    // ---- hoist loop-invariants into registers ----
    float qreg[8];
    {
        uint4 qv = *(const uint4*)(qkv + (size_t)n * QKVD + h * 64 + cg * 8);
        const unsigned short* qs = (const unsigned short*)&qv;
#pragma unroll
        for (int j = 0; j < 8; ++j) qreg[j] = b2f(*(const bf16*)&qs[j]);
    }
    fv4 qg = (fv4)(0.0f);
    if (cg < 6) qg = *(const fv4*)(pts + (size_t)n * PTSD + h * 24 + cg * 4);
    float wb[16];
#pragma unroll
    for (int j = 0; j < 16; ++j) wb[j] = Wb[(cg + 8 * j) * 8 + h];  // Wb 4KB, hot

    __syncthreads();

    // ---- logits: wave w owns k = w*8 .. w*8+7 ----
#pragma unroll
    for (int kk = 0; kk < 8; ++kk) {
        int k = w * 8 + kk;
        int nb = nbS[k];
        uint4 kv = *(const uint4*)(qkv + (size_t)nb * QKVD + 512 + h * 64 + cg * 8);
        const unsigned short* ks = (const unsigned short*)&kv;
        float dot = 0.0f;
#pragma unroll
        for (int j = 0; j < 8; ++j) dot += qreg[j] * b2f(*(const bf16*)&ks[j]);
        float d2 = 0.0f;
        if (cg < 6) {
            fv4 kg = *(const fv4*)(pts + (size_t)nb * PTSD + 192 + h * 24 + cg * 4);
            float dx = qg.x - kg.x, dy = qg.y - kg.y, dz = qg.z - kg.z, dw = qg.w - kg.w;
            d2 = dx*dx + dy*dy + dz*dz + dw*dw;
        }
        float bias = 0.0f;
#pragma unroll
        for (int j = 0; j < 16; ++j) bias += pairS[k][cg + 8 * j] * wb[j];

        float val = 0.125f * dot + bias - dfS[h] * d2;
        val += __shfl_xor(val, 1, 64);
        val += __shfl_xor(val, 2, 64);
        val += __shfl_xor(val, 4, 64);
        if (cg == 0) logitS[k][h] = 0.5773502691896258f * val;
    }
    __syncthreads();

    // ---- softmax over k, one wave: lane = h*8 + j, j owns k = j + 8i ----
    if (tid < 64) {
        int hh = tid >> 3, j = tid & 7;
        float l[4];
        float m = -1e30f;
#pragma unroll
        for (int i = 0; i < 4; ++i) { l[i] = logitS[j + 8 * i][hh]; m = fmaxf(m, l[i]); }
        m = fmaxf(m, __shfl_xor(m, 1, 64));
        m = fmaxf(m, __shfl_xor(m, 2, 64));
        m = fmaxf(m, __shfl_xor(m, 4, 64));
        float s = 0.0f;
#pragma unroll
        for (int i = 0; i < 4; ++i) { l[i] = expf(l[i] - m); s += l[i]; }
        s += __shfl_xor(s, 1, 64);
        s += __shfl_xor(s, 2, 64);
        s += __shfl_xor(s, 4, 64);
        float inv = 1.0f / s;
#pragma unroll
        for (int i = 0; i < 4; ++i) attnS[j + 8 * i][hh] = l[i] * inv;
    }
    __syncthreads();

    bf16* fr = (bf16*)(pair + (size_t)n * PAIR_ROW);  // feats row
    // ---- out_pair: 1024 = H*CP; thread owns 4 consecutive c (ds_read_b128) --
    {
        int hh = tid >> 5;           // 0..7
        int c4 = (tid & 31) * 4;     // 0..124
        float a0 = 0.0f, a1 = 0.0f, a2 = 0.0f, a3 = 0.0f;
#pragma unroll
        for (int k = 0; k < KNBR; ++k) {
            fv4 p = *(const fv4*)&pairS[k][c4];
            float a = attnS[k][hh];
            a0 += a * p.x; a1 += a * p.y; a2 += a * p.z; a3 += a * p.w;
        }
        unsigned int lo = (unsigned int)f2u(a0) | ((unsigned int)f2u(a1) << 16);
        unsigned int hi = (unsigned int)f2u(a2) | ((unsigned int)f2u(a3) << 16);
        uint2 pk; pk.x = lo; pk.y = hi;
        *(uint2*)(fr + hh * 128 + c4) = pk;
    }
    // ---- out_scalar: 512 = H*S (coalesced v gathers) ----
    for (int e = tid; e < 512; e += 256) {
        int hh = e >> 6, c = e & 63;
        float acc = 0.0f;
#pragma unroll
        for (int k = 0; k < KNBR; ++k)
            acc += attnS[k][hh] * b2f(qkv[(size_t)nbS[k] * QKVD + 1024 + hh * 64 + c]);
        fr[1024 + e] = f2b(acc);
    }
    // ---- op: 192 threads, coalesced per-k v_g rows ----
    if (tid < 192) {
        int hh = tid / 24;
        float acc = 0.0f;
#pragma unroll
        for (int k = 0; k < KNBR; ++k)
            acc += attnS[k][hh] * pts[(size_t)nbS[k] * PTSD + 384 + tid];
        gS[tid] = acc;
    }
    __syncthreads();
    if (tid < 64) {
        int hh = tid >> 3, p = tid & 7;
        const float* t = tv + (size_t)n * 3;
        const float* R = Rm + (size_t)n * 9;
        float gx = gS[hh * 24 + p * 3 + 0] - t[0];
        float gy = gS[hh * 24 + p * 3 + 1] - t[1];
        float gz = gS[hh * 24 + p * 3 + 2] - t[2];
        // einsum('nji,...j->...i') = R^T g
        float o0 = R[0]*gx + R[3]*gy + R[6]*gz;
        float o1 = R[1]*gx + R[4]*gy + R[7]*gz;
        float o2 = R[2]*gx + R[5]*gy + R[8]*gz;
        fr[1536 + hh*24 + p*3 + 0] = f2b(o0);
        fr[1536 + hh*24 + p*3 + 1] = f2b(o1);
        fr[1536 + hh*24 + p*3 + 2] = f2b(o2);
        fr[1728 + hh*8 + p] = f2b(sqrtf(o0*o0 + o1*o1 + o2*o2 + 1e-8f));
    }
}

// ---------------------------------------------------------------- launch ----
extern "C" void kernel_launch(void* const* d_in, const int* in_sizes, int n_in,
                              void* d_out, int out_size, void* d_ws, size_t ws_size,
                              hipStream_t stream) {
    const float* local      = (const float*)d_in[0];
    const float* pos        = (const float*)d_in[1];
    float*       pair       = (float*)d_in[2];    // feats written into it post-read
    const int*   neighbours = (const int*)d_in[4];
    const float* ln_s   = (const float*)d_in[9];
    const float* ln_b   = (const float*)d_in[10];
    const float* W_qkv  = (const float*)d_in[11];
    const float* ln_q_s = (const float*)d_in[12];
    const float* ln_q_b = (const float*)d_in[13];
    const float* ln_k_s = (const float*)d_in[14];
    const float* ln_k_b = (const float*)d_in[15];
    const float* W_pts  = (const float*)d_in[16];
    const float* W_bias = (const float*)d_in[17];
    const float* gamma  = (const float*)d_in[18];
    const float* W_out  = (const float*)d_in[19];
    const float* b_out  = (const float*)d_in[20];
    float* out = (float*)d_out;

    // ws (44,498,944 B): Rm | tv | pts | qkv.
    // d_out (25.17 MB) hosts xln (12.58 MB) + wtm (3.34 MB) until final GEMM.
    // wt3 (W_out^T, 2.75 MB) reuses pts region (pts dead after attn).
    float* Rm   = (float*)d_ws;                      // N*9
    float* tv   = Rm   + (size_t)NN * 9;             // N*3
    float* pts  = tv   + (size_t)NN * 3;             // N*576 fp32
    bf16*  qkv  = (bf16*)(pts + (size_t)NN * PTSD);  // N*1536 bf16
    bf16*  xln  = (bf16*)d_out;                      // N*768 bf16
    bf16*  wtm  = xln + (size_t)NN * DD;             // 2176*768 bf16
    bf16*  wt3  = (bf16*)pts;                        // 768*1792 bf16 (post-attn)

    // prep: frames + LN(local) + both wtm transposes (one dispatch)
    prep_kernel<<<NN + 1152 + 480, 256, 0, stream>>>(
        local, ln_s, ln_b, xln, pos, Rm, tv, W_qkv, W_pts, wtm);

    // [qkv | pts_raw] = xln @ wtm^T; LN(q,k) fused into epilogue
    mfma_gemm<1, 0><<<dim3(2176 / 128, NN / 128), 256, 0, stream>>>(
        xln, DD, wtm, DD, qkv, pts, 0, 2176, nullptr,
        ln_q_s, ln_q_b, ln_k_s, ln_k_b);

    rotate_pts_kernel<<<(NN * 192) / 256, 256, 0, stream>>>(pts, Rm, tv);

    attn_kernel<<<NN, 256, 0, stream>>>(qkv, pts, Rm, tv, pair, neighbours,
                                        W_bias, gamma);

    // out = feats @ W_out + b_out
    transpose_kernel<<<dim3(768 / 32, 1792 / 32), 256, 0, stream>>>(
        W_out, wt3, FEATD, DD, 0, 0, 0, 0);
    mfma_gemm<0, 1><<<dim3(768 / 128, NN / 128), 256, 0, stream>>>(
        (const bf16*)pair, PAIR_ROW * 2, wt3, FEATD, out, nullptr, DD, DD, b_out,
        nullptr, nullptr, nullptr, nullptr);
}

// Round 5
// 478.073 us; speedup vs baseline: 1.3924x; 1.0466x over previous
//
#include <hip/hip_runtime.h>
#include <hip/hip_bf16.h>

// All float inputs/outputs are FP32. bf16 only for MFMA operands/intermediates.

#define NN 8192
#define KNBR 32
#define DD 768
#define CPC 128
#define HH 8
#define FEATD 1792
#define QKVD 1536
#define PTSD 576      // H * 24 * 3
#define PAIR_ROW 4096 // K*CP fp32 elements per residue row of `pair`

typedef __hip_bfloat16 bf16;
typedef __attribute__((ext_vector_type(8))) short s8;   // 8 bf16 (4 VGPRs)
typedef __attribute__((ext_vector_type(4))) float f4;   // MFMA accumulator
typedef __attribute__((ext_vector_type(4))) float fv4;  // ext-vector float4

__device__ __forceinline__ float b2f(bf16 v) { return __bfloat162float(v); }
__device__ __forceinline__ bf16 f2b(float v) { return __float2bfloat16(v); }
__device__ __forceinline__ unsigned short f2u(float v) {
    bf16 h = __float2bfloat16(v);
    return *(unsigned short*)&h;
}
// async global->LDS DMA, 16B per lane, wave-uniform LDS base (m97 recipe)
__device__ __forceinline__ void gl_lds16(const void* g, void* l) {
    __builtin_amdgcn_global_load_lds(
        (const __attribute__((address_space(1))) void*)g,
        (__attribute__((address_space(3))) void*)l, 16, 0, 0);
}

// ---------------------------------------------------------- device: frames --
__device__ __forceinline__ void do_frames(int n, const float* __restrict__ pos,
                                          float* __restrict__ Rm,
                                          float* __restrict__ tv) {
    const float* p = pos + (size_t)n * 42;  // (14,3): N, CA, C first three
    float nx[3], ca[3], cc[3];
#pragma unroll
    for (int j = 0; j < 3; ++j) { nx[j] = p[j]; ca[j] = p[3+j]; cc[j] = p[6+j]; }
    float v1[3], v2[3], e1[3], e2[3], e3[3];
#pragma unroll
    for (int j = 0; j < 3; ++j) { v1[j] = cc[j] - ca[j]; v2[j] = nx[j] - ca[j]; }
    float s1 = v1[0]*v1[0] + v1[1]*v1[1] + v1[2]*v1[2];
    float r1 = 1.0f / sqrtf(s1 + 1e-8f);
#pragma unroll
    for (int j = 0; j < 3; ++j) e1[j] = v1[j] * r1;
    float d = v2[0]*e1[0] + v2[1]*e1[1] + v2[2]*e1[2];
    float u2[3];
#pragma unroll
    for (int j = 0; j < 3; ++j) u2[j] = v2[j] - d * e1[j];
    float s2 = u2[0]*u2[0] + u2[1]*u2[1] + u2[2]*u2[2];
    float r2 = 1.0f / sqrtf(s2 + 1e-8f);
#pragma unroll
    for (int j = 0; j < 3; ++j) e2[j] = u2[j] * r2;
    e3[0] = e1[1]*e2[2] - e1[2]*e2[1];
    e3[1] = e1[2]*e2[0] - e1[0]*e2[2];
    e3[2] = e1[0]*e2[1] - e1[1]*e2[0];
#pragma unroll
    for (int i = 0; i < 3; ++i) {
        Rm[(size_t)n*9 + i*3 + 0] = e1[i];
        Rm[(size_t)n*9 + i*3 + 1] = e2[i];
        Rm[(size_t)n*9 + i*3 + 2] = e3[i];
        tv[(size_t)n*3 + i] = ca[i];
    }
}

// ------------------------------------------------------- device: transpose --
// W: K x N (fp32) -> Wt: (rowoff+Npad) x K (bf16), zero rows >= N.
// cn != 0: head-segregation perm, old col h*group+seg*cn+c -> seg*segsz+h*cn+c.
__device__ __forceinline__ void do_transpose(const float* __restrict__ W,
                                             bf16* __restrict__ Wt,
                                             int K, int N, int group, int cn,
                                             int segsz, int rowoff,
                                             int bx, int by, int tid,
                                             char* shbuf) {
    bf16 (*tile)[33] = (bf16(*)[33])shbuf;  // 2112 B
    int n0 = bx * 32, k0 = by * 32;
    int r = tid >> 5, c = tid & 31;
    for (int rr = r; rr < 32; rr += 8) {
        int n = n0 + c;
        tile[rr][c] = (n < N) ? f2b(W[(size_t)(k0 + rr) * N + n]) : f2b(0.0f);
    }
    __syncthreads();
    for (int rr = r; rr < 32; rr += 8) {
        int n = n0 + rr;
        int pn = n;
        if (cn != 0 && n < N) {
            int hh = n / group, rm = n % group;
            pn = (rm / cn) * segsz + hh * cn + (rm % cn);
        }
        Wt[(size_t)(rowoff + pn) * K + k0 + c] = tile[c][rr];
    }
}

// ------------------------------------------------------------------- prep ----
// blocks [0,NN): LN(local) row b -> xln bf16 (+ frames for b<32, 1 res/thread)
// blocks [NN, NN+1152): transpose W_qkv -> wtm rows 0..1535 (q|k|v perm)
// blocks [NN+1152, NN+1632): transpose W_pts -> wtm rows 1536..2175 (perm, pad)
__global__ __launch_bounds__(256) void prep_kernel(
        const float* __restrict__ local, const float* __restrict__ lns,
        const float* __restrict__ lnb, bf16* __restrict__ xln,
        const float* __restrict__ pos, float* __restrict__ Rm,
        float* __restrict__ tv,
        const float* __restrict__ W_qkv, const float* __restrict__ W_pts,
        bf16* __restrict__ wtm) {
    __shared__ __align__(16) char shbuf[2560];
    int b = blockIdx.x, tid = threadIdx.x;
    if (b < NN) {
        if (b < 32) do_frames(b * 256 + tid, pos, Rm, tv);
        float* red = (float*)shbuf;
        const float* row = local + (size_t)b * DD;
        float v[3];
#pragma unroll
        for (int e = 0; e < 3; ++e) v[e] = row[tid + 256*e];
        red[tid] = v[0] + v[1] + v[2];
        __syncthreads();
        for (int st = 128; st > 0; st >>= 1) {
            if (tid < st) red[tid] += red[tid + st];
            __syncthreads();
        }
        float mean = red[0] * (1.0f / DD);
        __syncthreads();
        float d0 = v[0]-mean, d1 = v[1]-mean, d2 = v[2]-mean;
        red[tid] = d0*d0 + d1*d1 + d2*d2;
        __syncthreads();
        for (int st = 128; st > 0; st >>= 1) {
            if (tid < st) red[tid] += red[tid + st];
            __syncthreads();
        }
        float rstd = rsqrtf(red[0] * (1.0f / DD) + 1e-5f);
        bf16* orow = xln + (size_t)b * DD;
#pragma unroll
        for (int e = 0; e < 3; ++e) {
            int c = tid + 256*e;
            orow[c] = f2b((v[e] - mean) * rstd * lns[c] + lnb[c]);
        }
    } else if (b < NN + 1152) {
        int t = b - NN;
        do_transpose(W_qkv, wtm, 768, 1536, 192, 64, 512, 0, t % 48, t / 48,
                     tid, shbuf);
    } else {
        int t = b - NN - 1152;
        do_transpose(W_pts, wtm, 768, PTSD, 72, 24, 192, 1536, t % 20, t / 20,
                     tid, shbuf);
    }
}

// ----------------------------------------------------- weight transpose -----
// standalone (wt3 must wait until pts region is dead, post-attn)
__global__ __launch_bounds__(256) void transpose_kernel(const float* __restrict__ W,
                                                        bf16* __restrict__ Wt,
                                                        int K, int N,
                                                        int group, int cn, int segsz,
                                                        int rowoff) {
    __shared__ __align__(16) char shbuf[2560];
    do_transpose(W, Wt, K, N, group, cn, segsz, rowoff,
                 blockIdx.x, blockIdx.y, threadIdx.x, shbuf);
}

// ------------------------------------------------------------ MFMA GEMM -----
// C = A[M x K](bf16) @ Bt^T (Bt stored N x K bf16, pre-transposed).
// 128x128 tile, BK=32, 4 waves x (4x4) mfma_f32_16x16x32_bf16,
// global_load_lds dwordx4 staging (m97 structure).
// XCD-aware tile swizzle (T1): grid size is a multiple of 8, each XCD gets a
// contiguous run of tiles (x-fastest) -> shared A-panels stay in its L2.
// SPLIT=0: fp32 C (+bias if BIAS) with ncols guard.
// SPLIT=1: cols <  1024 -> per-head LN(q/k) over the wave's 64-col slice
//                          (fp32 stats via shfl_xor over lr bits) -> bf16 C;
//          cols < QKVD   -> v passthrough bf16;
//          cols >= QKVD  -> fp32 into C2 (pts, guard col-QKVD < PTSD).
template<int SPLIT, int BIAS>
__global__ __launch_bounds__(256) void mfma_gemm(const bf16* __restrict__ A, int lda,
                                                 const bf16* __restrict__ Bt, int K,
                                                 void* __restrict__ C,
                                                 void* __restrict__ C2,
                                                 int ldc, int ncols,
                                                 const float* __restrict__ bias,
                                                 const float* __restrict__ lnqs,
                                                 const float* __restrict__ lnqb,
                                                 const float* __restrict__ lnks,
                                                 const float* __restrict__ lnkb) {
    __shared__ short As[128 * 32];   // [row][k] bf16 bits, 8 KB
    __shared__ short Bs[128 * 32];   // [n][k]  bf16 bits, 8 KB
    int tid = threadIdx.x;
    int w = tid >> 6, lane = tid & 63;
    int q = lane >> 4, lr = lane & 15;
    // XCD swizzle (nwg % 8 == 0 for all launches here)
    int bid = blockIdx.y * gridDim.x + blockIdx.x;
    int cpx = (gridDim.x * gridDim.y) >> 3;
    int swz = (bid & 7) * cpx + (bid >> 3);
    int bx = swz % gridDim.x, by = swz / gridDim.x;
    int m0 = by * 128, n0 = bx * 128;
    int lrow = lane >> 2, lcol = (lane & 3) * 8;   // DMA lane mapping

    f4 acc[4][4] = {};

    for (int k0 = 0; k0 < K; k0 += 32) {
#pragma unroll
        for (int i = 0; i < 2; ++i) {
            int c = w * 2 + i;
            int r = c * 16 + lrow;
            gl_lds16(A  + (size_t)(m0 + r) * lda + k0 + lcol, As + c * 512);
            gl_lds16(Bt + (size_t)(n0 + r) * K   + k0 + lcol, Bs + c * 512);
        }
        __syncthreads();   // drains vmcnt(0): DMA complete for all waves

        const short* Ab = As + ((w & 1) * 64 + lr) * 32 + q * 8;
        const short* Bb = Bs + ((w >> 1) * 64 + lr) * 32 + q * 8;
        s8 af[4], bfr[4];
#pragma unroll
        for (int i = 0; i < 4; ++i) af[i] = *(const s8*)(Ab + i * 16 * 32);
#pragma unroll
        for (int j = 0; j < 4; ++j) bfr[j] = *(const s8*)(Bb + j * 16 * 32);
#pragma unroll
        for (int i = 0; i < 4; ++i)
#pragma unroll
            for (int j = 0; j < 4; ++j)
                acc[i][j] = __builtin_amdgcn_mfma_f32_16x16x32_bf16(
                    af[i], bfr[j], acc[i][j], 0, 0, 0);
        __syncthreads();
    }

    // ---- epilogue: C/D layout col=lane&15, row=(lane>>4)*4+reg ----
    int mb = m0 + (w & 1) * 64, nb = n0 + (w >> 1) * 64;
    if (!SPLIT) {
#pragma unroll
        for (int i = 0; i < 4; ++i)
#pragma unroll
            for (int j = 0; j < 4; ++j) {
                int col = nb + j * 16 + lr;
                int row0 = mb + i * 16 + q * 4;
                if (col < ncols) {
#pragma unroll
                    for (int r = 0; r < 4; ++r) {
                        float v = acc[i][j][r];
                        if (BIAS) v += bias[col];
                        ((float*)C)[(size_t)(row0 + r) * ldc + col] = v;
                    }
                }
            }
    } else if (nb < 1024) {
        // fused per-head LN over the wave's 64-col q/k slice (fp32 stats)
        const float* sc = (nb < 512) ? lnqs : lnks;
        const float* of = (nb < 512) ? lnqb : lnkb;
        float scv[4], ofv[4];
#pragma unroll
        for (int j = 0; j < 4; ++j) { scv[j] = sc[j*16 + lr]; ofv[j] = of[j*16 + lr]; }
#pragma unroll
        for (int i = 0; i < 4; ++i) {
#pragma unroll
            for (int r = 0; r < 4; ++r) {
                float s = acc[i][0][r] + acc[i][1][r] + acc[i][2][r] + acc[i][3][r];
                s += __shfl_xor(s, 1, 64); s += __shfl_xor(s, 2, 64);
                s += __shfl_xor(s, 4, 64); s += __shfl_xor(s, 8, 64);
                float mean = s * (1.0f / 64.0f);
                float d0 = acc[i][0][r] - mean, d1 = acc[i][1][r] - mean;
                float d2 = acc[i][2][r] - mean, d3 = acc[i][3][r] - mean;
                float vs = d0*d0 + d1*d1 + d2*d2 + d3*d3;
                vs += __shfl_xor(vs, 1, 64); vs += __shfl_xor(vs, 2, 64);
                vs += __shfl_xor(vs, 4, 64); vs += __shfl_xor(vs, 8, 64);
                float rstd = rsqrtf(vs * (1.0f / 64.0f) + 1e-5f);
                unsigned short* Crow =
                    (unsigned short*)C + (size_t)(mb + i*16 + q*4 + r) * QKVD + nb;
                Crow[0*16 + lr] = f2u(d0 * rstd * scv[0] + ofv[0]);
                Crow[1*16 + lr] = f2u(d1 * rstd * scv[1] + ofv[1]);
                Crow[2*16 + lr] = f2u(d2 * rstd * scv[2] + ofv[2]);
                Crow[3*16 + lr] = f2u(d3 * rstd * scv[3] + ofv[3]);
            }
        }
    } else if (nb < QKVD) {
        // v passthrough
#pragma unroll
        for (int i = 0; i < 4; ++i)
#pragma unroll
            for (int j = 0; j < 4; ++j) {
                int col = nb + j * 16 + lr;
                int row0 = mb + i * 16 + q * 4;
#pragma unroll
                for (int r = 0; r < 4; ++r)
                    ((unsigned short*)C)[(size_t)(row0 + r) * QKVD + col] =
                        f2u(acc[i][j][r]);
            }
    } else {
        // pts fp32
#pragma unroll
        for (int i = 0; i < 4; ++i)
#pragma unroll
            for (int j = 0; j < 4; ++j) {
                int col = nb + j * 16 + lr;
                int row0 = mb + i * 16 + q * 4;
                if (col - QKVD < PTSD) {
                    int pc = col - QKVD;
#pragma unroll
                    for (int r = 0; r < 4; ++r)
                        ((float*)C2)[(size_t)(row0 + r) * PTSD + pc] = acc[i][j][r];
                }
            }
    }
}

// -------------------------------------------------------- rotate points -----
__global__ __launch_bounds__(256) void rotate_pts_kernel(float* __restrict__ pts,
                                                         const float* __restrict__ Rm,
                                                         const float* __restrict__ tv) {
    int idx = blockIdx.x * blockDim.x + threadIdx.x;  // over N*192
    if (idx >= NN * 192) return;
    int n = idx / 192;
    int rem = idx % 192;
    float* base = pts + (size_t)n * PTSD + rem * 3;
    float r0 = base[0], r1 = base[1], r2 = base[2];
    const float* R = Rm + (size_t)n * 9;
    const float* t = tv + (size_t)n * 3;
    base[0] = R[0]*r0 + R[1]*r1 + R[2]*r2 + t[0];
    base[1] = R[3]*r0 + R[4]*r1 + R[5]*r2 + t[1];
    base[2] = R[6]*r0 + R[7]*r1 + R[8]*r2 + t[2];
}

// ------------------------------------------------------------- attention ----
// Segregated layouts:
//   qkv row: [q: h*64+c | 512 + k: h*64+c | 1024 + v: h*64+c]
//   pts row: [qg: h*24+e | 192 + kg: h*24+e | 384 + vg: h*24+e]  (e = p*3+d)
// Restructured for latency overlap:
//  - pair NT loads -> regs, k/kg gathers -> explicit arrays (deep MLP),
//    dot/dist computed pre-barrier; bias (needs pairS) post-barrier.
//  - output: out_pair on all waves, then wave 0 = out_scalar (16B v-gathers),
//    waves 1-3 = op (192 threads) run concurrently.
__global__ __launch_bounds__(256) void attn_kernel(const bf16* __restrict__ qkv,
                                                   const float* __restrict__ pts,
                                                   const float* __restrict__ Rm,
                                                   const float* __restrict__ tv,
                                                   float* __restrict__ pair,
                                                   const int* __restrict__ nbr,
                                                   const float* __restrict__ Wb,
                                                   const float* __restrict__ gamma) {
    int n = blockIdx.x;
    int tid = threadIdx.x;
    int w = tid >> 6, lane = tid & 63;
    int h = lane >> 3, cg = lane & 7;

    __shared__ float pairS[32][132];  // pad 132: float4-aligned, conflict-free
    __shared__ float logitS[32][8];
    __shared__ float attnS[32][8];
    __shared__ float gS[192];
    __shared__ int nbS[32];
    __shared__ float dfS[8];

    // ---- 1. pair row NT loads -> regs (evict-first; keep L3 for gathers) ----
    const fv4* pr4 = (const fv4*)(pair + (size_t)n * PAIR_ROW);
    fv4 pv[4];
#pragma unroll
    for (int i = 0; i < 4; ++i) pv[i] = __builtin_nontemporal_load(pr4 + tid + 256*i);

    // ---- 2. per-wave neighbor indices (wave-uniform 4B loads, cached) ----
    const int* nrow = nbr + (size_t)n * KNBR + w * 8;
    int nb_[8];
#pragma unroll
    for (int kk = 0; kk < 8; ++kk) nb_[kk] = nrow[kk];

    // ---- 3. issue all k / k_g gathers into register arrays ----
    uint4 kv[8];
#pragma unroll
    for (int kk = 0; kk < 8; ++kk)
        kv[kk] = *(const uint4*)(qkv + (size_t)nb_[kk] * QKVD + 512 + h * 64 + cg * 8);
    fv4 kg[8];
    if (cg < 6) {
#pragma unroll
        for (int kk = 0; kk < 8; ++kk)
            kg[kk] = *(const fv4*)(pts + (size_t)nb_[kk] * PTSD + 192 + h * 24 + cg * 4);
    } else {
#pragma unroll
        for (int kk = 0; kk < 8; ++kk) kg[kk] = (fv4)(0.0f);
    }

    // ---- 4. loop invariants ----
    float qreg[8];
    {
        uint4 qv = *(const uint4*)(qkv + (size_t)n * QKVD + h * 64 + cg * 8);
        const unsigned short* qs = (const unsigned short*)&qv;
#pragma unroll
        for (int j = 0; j < 8; ++j) qreg[j] = b2f(*(const bf16*)&qs[j]);
    }
    fv4 qg = (fv4)(0.0f);
    if (cg < 6) qg = *(const fv4*)(pts + (size_t)n * PTSD + h * 24 + cg * 4);
    float wb[16];
#pragma unroll
    for (int j = 0; j < 16; ++j) wb[j] = Wb[(cg + 8 * j) * 8 + h];

    // ---- 5. LDS writes ----
#pragma unroll
    for (int i = 0; i < 4; ++i) {
        int e = tid + 256 * i;
        *(fv4*)&pairS[e >> 5][(e & 31) * 4] = pv[i];
    }
    if (tid < 32) nbS[tid] = nbr[(size_t)n * KNBR + tid];
    if (tid < 8) dfS[tid] = log1pf(expf(gamma[tid])) * (1.0f / 12.0f);

    // ---- 6. dot/dist partials from register arrays (pre-barrier) ----
    float pdot[8], pd2[8];
#pragma unroll
    for (int kk = 0; kk < 8; ++kk) {
        const unsigned short* ks = (const unsigned short*)&kv[kk];
        float dot = 0.0f;
#pragma unroll
        for (int j = 0; j < 8; ++j) dot += qreg[j] * b2f(*(const bf16*)&ks[j]);
        pdot[kk] = dot;
        float dx = qg.x - kg[kk].x, dy = qg.y - kg[kk].y;
        float dz = qg.z - kg[kk].z, dw = qg.w - kg[kk].w;
        pd2[kk] = dx*dx + dy*dy + dz*dz + dw*dw;   // 0 for cg>=6 (both zero)
    }
    __syncthreads();

    // ---- 7. bias from pairS + combine + reduce ----
#pragma unroll
    for (int kk = 0; kk < 8; ++kk) {
        int k = w * 8 + kk;
        float bias = 0.0f;
#pragma unroll
        for (int j = 0; j < 16; ++j) bias += pairS[k][cg + 8 * j] * wb[j];
        float val = 0.125f * pdot[kk] + bias - dfS[h] * pd2[kk];
        val += __shfl_xor(val, 1, 64);
        val += __shfl_xor(val, 2, 64);
        val += __shfl_xor(val, 4, 64);
        if (cg == 0) logitS[k][h] = 0.5773502691896258f * val;
    }
    __syncthreads();

    // ---- softmax over k, one wave: lane = h*8 + j, j owns k = j + 8i ----
    if (tid < 64) {
        int hh = tid >> 3, j = tid & 7;
        float l[4];
        float m = -1e30f;
#pragma unroll
        for (int i = 0; i < 4; ++i) { l[i] = logitS[j + 8 * i][hh]; m = fmaxf(m, l[i]); }
        m = fmaxf(m, __shfl_xor(m, 1, 64));
        m = fmaxf(m, __shfl_xor(m, 2, 64));
        m = fmaxf(m, __shfl_xor(m, 4, 64));
        float s = 0.0f;
#pragma unroll
        for (int i = 0; i < 4; ++i) { l[i] = expf(l[i] - m); s += l[i]; }
        s += __shfl_xor(s, 1, 64);
        s += __shfl_xor(s, 2, 64);
        s += __shfl_xor(s, 4, 64);
        float inv = 1.0f / s;
#pragma unroll
        for (int i = 0; i < 4; ++i) attnS[j + 8 * i][hh] = l[i] * inv;
    }
    __syncthreads();

    bf16* fr = (bf16*)(pair + (size_t)n * PAIR_ROW);  // feats row
    // ---- out_pair: 1024 = H*CP (round-3 proven form) ----
    for (int e = tid; e < 1024; e += 256) {
        int hh = e >> 7, c = e & 127;
        float acc = 0.0f;
#pragma unroll
        for (int k = 0; k < KNBR; ++k) acc += attnS[k][hh] * pairS[k][c];
        fr[e] = f2b(acc);
    }
    // ---- wave-split: wave 0 out_scalar (vector v-gathers), waves 1-3 op ----
    if (tid < 64) {
        int hh = lane >> 3, c8 = (lane & 7) * 8;
        float a8[8] = {};
#pragma unroll
        for (int k = 0; k < KNBR; ++k) {
            float a = attnS[k][hh];
            uint4 vv = *(const uint4*)(qkv + (size_t)nbS[k] * QKVD + 1024 + hh * 64 + c8);
            const unsigned short* vs = (const unsigned short*)&vv;
#pragma unroll
            for (int j = 0; j < 8; ++j) a8[j] += a * b2f(*(const bf16*)&vs[j]);
        }
        unsigned short o[8];
#pragma unroll
        for (int j = 0; j < 8; ++j) o[j] = f2u(a8[j]);
        *(uint4*)(fr + 1024 + hh * 64 + c8) = *(const uint4*)o;
    } else {
        int t = tid - 64;            // 0..191
        int hh = t / 24;
        float acc = 0.0f;
#pragma unroll
        for (int k = 0; k < KNBR; ++k)
            acc += attnS[k][hh] * pts[(size_t)nbS[k] * PTSD + 384 + t];
        gS[t] = acc;
    }
    __syncthreads();
    if (tid < 64) {
        int hh = tid >> 3, p = tid & 7;
        const float* t = tv + (size_t)n * 3;
        const float* R = Rm + (size_t)n * 9;
        float gx = gS[hh * 24 + p * 3 + 0] - t[0];
        float gy = gS[hh * 24 + p * 3 + 1] - t[1];
        float gz = gS[hh * 24 + p * 3 + 2] - t[2];
        // einsum('nji,...j->...i') = R^T g
        float o0 = R[0]*gx + R[3]*gy + R[6]*gz;
        float o1 = R[1]*gx + R[4]*gy + R[7]*gz;
        float o2 = R[2]*gx + R[5]*gy + R[8]*gz;
        fr[1536 + hh*24 + p*3 + 0] = f2b(o0);
        fr[1536 + hh*24 + p*3 + 1] = f2b(o1);
        fr[1536 + hh*24 + p*3 + 2] = f2b(o2);
        fr[1728 + hh*8 + p] = f2b(sqrtf(o0*o0 + o1*o1 + o2*o2 + 1e-8f));
    }
}

// ---------------------------------------------------------------- launch ----
extern "C" void kernel_launch(void* const* d_in, const int* in_sizes, int n_in,
                              void* d_out, int out_size, void* d_ws, size_t ws_size,
                              hipStream_t stream) {
    const float* local      = (const float*)d_in[0];
    const float* pos        = (const float*)d_in[1];
    float*       pair       = (float*)d_in[2];    // feats written into it post-read
    const int*   neighbours = (const int*)d_in[4];
    const float* ln_s   = (const float*)d_in[9];
    const float* ln_b   = (const float*)d_in[10];
    const float* W_qkv  = (const float*)d_in[11];
    const float* ln_q_s = (const float*)d_in[12];
    const float* ln_q_b = (const float*)d_in[13];
    const float* ln_k_s = (const float*)d_in[14];
    const float* ln_k_b = (const float*)d_in[15];
    const float* W_pts  = (const float*)d_in[16];
    const float* W_bias = (const float*)d_in[17];
    const float* gamma  = (const float*)d_in[18];
    const float* W_out  = (const float*)d_in[19];
    const float* b_out  = (const float*)d_in[20];
    float* out = (float*)d_out;

    // ws (44,498,944 B): Rm | tv | pts | qkv.
    // d_out (25.17 MB) hosts xln (12.58 MB) + wtm (3.34 MB) until final GEMM.
    // wt3 (W_out^T, 2.75 MB) reuses pts region (pts dead after attn).
    float* Rm   = (float*)d_ws;                      // N*9
    float* tv   = Rm   + (size_t)NN * 9;             // N*3
    float* pts  = tv   + (size_t)NN * 3;             // N*576 fp32
    bf16*  qkv  = (bf16*)(pts + (size_t)NN * PTSD);  // N*1536 bf16
    bf16*  xln  = (bf16*)d_out;                      // N*768 bf16
    bf16*  wtm  = xln + (size_t)NN * DD;             // 2176*768 bf16
    bf16*  wt3  = (bf16*)pts;                        // 768*1792 bf16 (post-attn)

    // prep: frames + LN(local) + both wtm transposes (one dispatch)
    prep_kernel<<<NN + 1152 + 480, 256, 0, stream>>>(
        local, ln_s, ln_b, xln, pos, Rm, tv, W_qkv, W_pts, wtm);

    // [qkv | pts_raw] = xln @ wtm^T; LN(q,k) fused into epilogue
    mfma_gemm<1, 0><<<dim3(2176 / 128, NN / 128), 256, 0, stream>>>(
        xln, DD, wtm, DD, qkv, pts, 0, 2176, nullptr,
        ln_q_s, ln_q_b, ln_k_s, ln_k_b);

    rotate_pts_kernel<<<(NN * 192) / 256, 256, 0, stream>>>(pts, Rm, tv);

    attn_kernel<<<NN, 256, 0, stream>>>(qkv, pts, Rm, tv, pair, neighbours,
                                        W_bias, gamma);

    // out = feats @ W_out + b_out
    transpose_kernel<<<dim3(768 / 32, 1792 / 32), 256, 0, stream>>>(
        W_out, wt3, FEATD, DD, 0, 0, 0, 0);
    mfma_gemm<0, 1><<<dim3(768 / 128, NN / 128), 256, 0, stream>>>(
        (const bf16*)pair, PAIR_ROW * 2, wt3, FEATD, out, nullptr, DD, DD, b_out,
        nullptr, nullptr, nullptr, nullptr);
}